// Round 2
// baseline (449.530 us; speedup 1.0000x reference)
//
#include <hip/hip_runtime.h>
#include <hip/hip_cooperative_groups.h>
#include <math.h>

namespace cg = cooperative_groups;

#define Bsz 4
#define DM 96
#define DI 192
#define NS 16
#define RK 6
#define KK 4
#define HH 32
#define WW 32
#define LL 1024
#define NC 32          // chunks along L
#define CS 32          // chunk size (NC*CS == LL)

__device__ __forceinline__ float silu_f(float x) { return x / (1.f + __expf(-x)); }

// forward snake map: scan position l -> flat spatial index hw for direction k
__device__ __forceinline__ int hw_of_l(int k, int l) {
    int a = l >> 5, r = l & 31;
    int m = (a & 1) ? 31 - r : r;
    int h, w;
    if (k < 2) { w = a; h = m; }      // vertical snake
    else       { h = a; w = m; }      // horizontal snake
    if (k & 1) { h = 31 - h; w = 31 - w; }
    return h * 32 + w;
}

// ---- in_proj: 8 outputs per thread; also zeroes stats ---------------------
__global__ void in_proj_k(const float* __restrict__ x, const float* __restrict__ w,
                          float* __restrict__ xx, float* __restrict__ zs,
                          float* __restrict__ stats) {
    int bi = blockIdx.x;                 // 4 lblk * 48 og * 4 b
    int t = threadIdx.x;
    if (bi == 0 && t < 2 * Bsz) stats[t] = 0.f;
    int lb = bi & 3;
    int og = (bi >> 2) % 48;
    int b = bi / 192;
    int l = lb * 256 + t;
    const float* xb = x + (size_t)b * DM * LL + l;
    float acc[8];
#pragma unroll
    for (int g = 0; g < 8; g++) acc[g] = 0.f;
    for (int c = 0; c < DM; c++) {
        float xv = xb[(size_t)c * LL];
#pragma unroll
        for (int g = 0; g < 8; g++)
            acc[g] = fmaf(xv, w[(size_t)(og * 8 + g) * DM + c], acc[g]);
    }
#pragma unroll
    for (int g = 0; g < 8; g++) {
        int o = og * 8 + g;
        if (o < DI) xx[((size_t)b * DI + o) * LL + l] = acc[g];
        else        zs[((size_t)b * DI + (o - DI)) * LL + l] = silu_f(acc[g]);
    }
}

// ---- depthwise conv3x3+silu -> transposed layout xxT[b][hw][d] ------------
__global__ void convT_k(const float* __restrict__ xx, const float* __restrict__ cw,
                        const float* __restrict__ cb, float* __restrict__ xxT) {
    __shared__ float tile[32][65];
    int bi = blockIdx.x;                 // 32 rows * 3 dtiles * 4 b
    int h0 = bi % 32;
    int dt = (bi / 32) % 3;
    int b = bi / 96;
    int d0 = dt * 64;
    int t = threadIdx.x;
    int wi = t & 31, dg = t >> 5;

#pragma unroll
    for (int pass = 0; pass < 8; pass++) {
        int di = pass * 8 + dg;
        int d = d0 + di;
        const float* xp = xx + ((size_t)b * DI + d) * LL;
        const float* wp = cw + d * 9;
        float acc = cb[d];
#pragma unroll
        for (int kh = 0; kh < 3; kh++) {
            int hh = h0 + kh - 1;
            if (hh < 0 || hh >= HH) continue;
#pragma unroll
            for (int kw = 0; kw < 3; kw++) {
                int ww2 = wi + kw - 1;
                if (ww2 < 0 || ww2 >= WW) continue;
                acc = fmaf(xp[hh * WW + ww2], wp[kh * 3 + kw], acc);
            }
        }
        tile[wi][di] = silu_f(acc);
    }
    __syncthreads();

    int di = t & 63, w4 = t >> 6;
#pragma unroll
    for (int rep = 0; rep < 8; rep++) {
        int w2 = rep * 4 + w4;
        xxT[((size_t)b * LL + h0 * 32 + w2) * DI + d0 + di] = tile[w2][di];
    }
}

// ---- x_dbl: tiled GEMM; stage 64 gathered rows of xxT, output [bk][l][38] -
__global__ void __launch_bounds__(512)
xdbl_k(const float* __restrict__ xxT, const float* __restrict__ xpw,
       float* __restrict__ xdbl) {
    __shared__ float tile[64 * 193];
    int blk = blockIdx.x;            // bk*16 + lt
    int bk = blk >> 4, lt = blk & 15;
    int k = bk & 3, b = bk >> 2;
    int t = threadIdx.x;

    const float* xb = xxT + (size_t)b * LL * DI;
#pragma unroll
    for (int i = 0; i < 6; i++) {
        int j4 = t + i * 512;
        int lr = j4 / 48;            // 48 float4 per row
        int d4 = j4 % 48;
        int hw = hw_of_l(k, lt * 64 + lr);
        float4 v = ((const float4*)(xb + (size_t)hw * DI))[d4];
        float* dst = &tile[lr * 193 + d4 * 4];
        dst[0] = v.x; dst[1] = v.y; dst[2] = v.z; dst[3] = v.w;
    }
    __syncthreads();

    int ll = t & 63;                 // lane -> l (2-way bank = free)
    int cg = t >> 6;                 // wave-uniform c-group 0..7
    int c0 = cg * 5;
    int wlim = (c0 + 5 <= 38) ? 5 : (38 - c0);   // 5,...,5,3
    const float* wk = xpw + (size_t)k * 38 * DI;

    float acc[5];
#pragma unroll
    for (int j = 0; j < 5; j++) acc[j] = 0.f;
    const float* xrow = &tile[ll * 193];
#pragma unroll 4
    for (int d = 0; d < DI; d++) {
        float xv = xrow[d];
#pragma unroll
        for (int j = 0; j < 5; j++) {
            int cc = c0 + j; cc = (cc > 37) ? 37 : cc;
            acc[j] = fmaf(xv, wk[(size_t)cc * DI + d], acc[j]);
        }
    }
    float* orow = xdbl + ((size_t)bk * LL + lt * 64 + ll) * 38;
#pragma unroll
    for (int j = 0; j < 5; j++)
        if (j < wlim) orow[c0 + j] = acc[j];
}

// ---- fused p1 + mid + p3: one cooperative kernel --------------------------
// grid = 512 blocks (bk*NC + c) x 192 threads; 2 blocks/CU co-resident.
// LDS: u rows + xd rows staged once; dt stashed between phases.
__global__ void __launch_bounds__(192)
megascan_k(const float* __restrict__ xxT, const float* __restrict__ xdbl,
           const float* __restrict__ dtw_g, const float* __restrict__ dtb_g,
           const float* __restrict__ Alog, const float* __restrict__ Ds,
           float* __restrict__ Pst, float* __restrict__ Hst,
           float* __restrict__ ysm) {
    cg::grid_group grid = cg::this_grid();
    __shared__ float u_tile[CS * 193];     // [s][d], pad 193
    __shared__ float xd_tile[CS * 38];     // [s][c'] broadcast reads
    __shared__ float dt_tile[CS * 192];    // [s][d]

    int blk = blockIdx.x;
    int bk = blk >> 5, c = blk & 31;
    int k = bk & 3, b = bk >> 2;
    int t = threadIdx.x;

    // ---- stage u rows (gathered) as float4 and xd rows (contiguous)
    const float* xb = xxT + (size_t)b * LL * DI;
#pragma unroll
    for (int i = 0; i < 8; i++) {
        int j4 = t + i * 192;            // 1536 float4 = 32 rows * 48
        int s = j4 / 48, d4 = j4 % 48;
        int hw = hw_of_l(k, c * CS + s);
        float4 v = ((const float4*)(xb + (size_t)hw * DI))[d4];
        float* dst = &u_tile[s * 193 + d4 * 4];
        dst[0] = v.x; dst[1] = v.y; dst[2] = v.z; dst[3] = v.w;
    }
    const float* xdsrc = xdbl + ((size_t)bk * LL + c * CS) * 38;
    for (int i = t; i < CS * 38; i += 192) xd_tile[i] = xdsrc[i];
    __syncthreads();

    int d = t;
    int kd = k * DI + d;

    float A[NS];
#pragma unroll
    for (int n = 0; n < NS; n++) A[n] = -__expf(Alog[(size_t)kd * NS + n]);
    float dtw[RK];
#pragma unroll
    for (int r = 0; r < RK; r++) dtw[r] = dtw_g[(size_t)kd * RK + r];
    float dtb = dtb_g[kd];
    float Dp = Ds[kd];

    // ---- phase A: local scan, stash dt
    float h[NS], P[NS];
#pragma unroll
    for (int n = 0; n < NS; n++) { h[n] = 0.f; P[n] = 1.f; }

    for (int s = 0; s < CS; s++) {
        const float* xd = &xd_tile[s * 38];
        float dt = dtb;
#pragma unroll
        for (int r = 0; r < RK; r++) dt = fmaf(xd[r], dtw[r], dt);
        dt = (dt > 20.f) ? dt : __logf(1.f + __expf(dt));
        dt_tile[s * 192 + d] = dt;
        float du = dt * u_tile[s * 193 + d];
#pragma unroll
        for (int n = 0; n < NS; n++) {
            float a = __expf(dt * A[n]);
            h[n] = fmaf(a, h[n], du * xd[6 + n]);
            P[n] *= a;
        }
    }
    size_t base = ((size_t)blk * DI + d) * NS;
#pragma unroll
    for (int n = 0; n < NS; n++) { Pst[base + n] = P[n]; Hst[base + n] = h[n]; }

    __threadfence();
    grid.sync();

    // ---- phase B: middle compose, 2 chains/thread (float2), depth-4 prefetch
    int gid = blk * 192 + t;
    if (gid < Bsz * KK * 1536) {
        int mbk = gid / 1536;
        int j = gid % 1536;
        const float2* Pp = (const float2*)(Pst + (size_t)mbk * NC * (DI * NS)) + j;
        float2* Hp = (float2*)(Hst + (size_t)mbk * NC * (DI * NS)) + j;
        const int S = (DI * NS) / 2;

        float2 hh = make_float2(0.f, 0.f);
        float2 Pr[4], Lr[4];
#pragma unroll
        for (int q = 0; q < 4; q++) { Pr[q] = Pp[(size_t)q * S]; Lr[q] = Hp[(size_t)q * S]; }
        for (int cc = 0; cc < NC; cc += 4) {
            float2 Pn[4], Ln[4];
            if (cc + 4 < NC) {
#pragma unroll
                for (int q = 0; q < 4; q++) {
                    Pn[q] = Pp[(size_t)(cc + 4 + q) * S];
                    Ln[q] = Hp[(size_t)(cc + 4 + q) * S];
                }
            }
#pragma unroll
            for (int q = 0; q < 4; q++) {
                Hp[(size_t)(cc + q) * S] = hh;
                hh.x = fmaf(Pr[q].x, hh.x, Lr[q].x);
                hh.y = fmaf(Pr[q].y, hh.y, Lr[q].y);
            }
#pragma unroll
            for (int q = 0; q < 4; q++) { Pr[q] = Pn[q]; Lr[q] = Ln[q]; }
        }
    }
    __threadfence();
    grid.sync();

    // ---- phase C: final scan from prefix, write y at spatial positions
#pragma unroll
    for (int n = 0; n < NS; n++) h[n] = Hst[base + n];
    float* yk = ysm + (size_t)bk * LL * DI;

    for (int s = 0; s < CS; s++) {
        const float* xd = &xd_tile[s * 38];
        float dt = dt_tile[s * 192 + d];
        float u = u_tile[s * 193 + d];
        float du = dt * u;
        float y = 0.f;
#pragma unroll
        for (int n = 0; n < NS; n++) {
            float a = __expf(dt * A[n]);
            h[n] = fmaf(a, h[n], du * xd[6 + n]);
            y = fmaf(h[n], xd[22 + n], y);
        }
        int hw = hw_of_l(k, c * CS + s);
        yk[(size_t)hw * DI + d] = fmaf(Dp, u, y);
    }
}

// ---- cross-merge: sequential reads (ysm is hw-ordered), stats -------------
#define MT 16
__global__ void merge_k(const float* __restrict__ ysm, float* __restrict__ ym,
                        float* __restrict__ stats) {
    __shared__ float tile[MT][DI + 1];
    __shared__ float sh1[3], sh2[3];
    int b = blockIdx.y;
    int hw0 = blockIdx.x * MT;
    int d = threadIdx.x;
    const float* yb = ysm + (size_t)b * KK * LL * DI;

    float s1 = 0.f, s2 = 0.f;
#pragma unroll
    for (int hwi = 0; hwi < MT; hwi++) {
        int hw = hw0 + hwi;
        float v = yb[((size_t)0 * LL + hw) * DI + d]
                + yb[((size_t)1 * LL + hw) * DI + d]
                + yb[((size_t)2 * LL + hw) * DI + d]
                + yb[((size_t)3 * LL + hw) * DI + d];
        tile[hwi][d] = v;
        s1 += v; s2 = fmaf(v, v, s2);
    }
#pragma unroll
    for (int off = 32; off > 0; off >>= 1) {
        s1 += __shfl_down(s1, off);
        s2 += __shfl_down(s2, off);
    }
    int lane = threadIdx.x & 63, wid = threadIdx.x >> 6;
    if (lane == 0) { sh1[wid] = s1; sh2[wid] = s2; }
    __syncthreads();
    if (threadIdx.x == 0) {
        atomicAdd(&stats[b * 2],     sh1[0] + sh1[1] + sh1[2]);
        atomicAdd(&stats[b * 2 + 1], sh2[0] + sh2[1] + sh2[2]);
    }
#pragma unroll
    for (int rep = 0; rep < MT; rep++) {
        int j = rep * DI + threadIdx.x;
        int d2 = j >> 4;
        int hwi = j & (MT - 1);
        ym[((size_t)b * DI + d2) * LL + hw0 + hwi] = tile[hwi][d2];
    }
}

// ---- fused norm + gate + out projection -----------------------------------
__global__ void outz_k(const float* __restrict__ ym, const float* __restrict__ zs,
                       const float* __restrict__ g, const float* __restrict__ be,
                       const float* __restrict__ stats, const float* __restrict__ wo,
                       float* __restrict__ out) {
    int bi = blockIdx.x;                 // 4 lblk * 24 og * 4 b
    int t = threadIdx.x;
    int lb = bi & 3;
    int og = (bi >> 2) % 24;
    int b = bi / 96;
    int l = lb * 256 + t;

    const float Ninv = 1.f / (float)(DI * LL);
    float mu = stats[b * 2] * Ninv;
    float var = stats[b * 2 + 1] * Ninv - mu * mu;
    float rstd = rsqrtf(var + 1e-6f);

    const float* yb = ym + (size_t)b * DI * LL + l;
    const float* zb = zs + (size_t)b * DI * LL + l;
    float acc[4];
#pragma unroll
    for (int gg = 0; gg < 4; gg++) acc[gg] = 0.f;
    for (int c = 0; c < DI; c++) {
        float v = (yb[(size_t)c * LL] - mu) * rstd * g[c] + be[c];
        float yv = v * zb[(size_t)c * LL];
#pragma unroll
        for (int gg = 0; gg < 4; gg++)
            acc[gg] = fmaf(yv, wo[(size_t)(og * 4 + gg) * DI + c], acc[gg]);
    }
#pragma unroll
    for (int gg = 0; gg < 4; gg++)
        out[((size_t)b * DM + og * 4 + gg) * LL + l] = acc[gg];
}

extern "C" void kernel_launch(void* const* d_in, const int* in_sizes, int n_in,
                              void* d_out, int out_size, void* d_ws, size_t ws_size,
                              hipStream_t stream) {
    const float* x    = (const float*)d_in[0];
    const float* ipw  = (const float*)d_in[1];
    const float* cw   = (const float*)d_in[2];
    const float* cb   = (const float*)d_in[3];
    const float* xpw  = (const float*)d_in[4];
    const float* dtw  = (const float*)d_in[5];
    const float* dtb  = (const float*)d_in[6];
    const float* Alog = (const float*)d_in[7];
    const float* Ds   = (const float*)d_in[8];
    const float* gng  = (const float*)d_in[9];
    const float* gnb  = (const float*)d_in[10];
    const float* opw  = (const float*)d_in[11];
    float* out = (float*)d_out;

    float* ws = (float*)d_ws;
    const size_t o_xx   = 0;                                       // (→ ym)
    const size_t o_zs   = o_xx   + (size_t)Bsz * DI * LL;
    const size_t o_xxT  = o_zs   + (size_t)Bsz * DI * LL;
    const size_t o_xdbl = o_xxT  + (size_t)Bsz * LL * DI;
    const size_t o_P    = o_xdbl + (size_t)Bsz * KK * LL * 38;
    const size_t o_H    = o_P    + (size_t)Bsz * KK * NC * DI * NS;
    const size_t o_ysm  = o_H    + (size_t)Bsz * KK * NC * DI * NS;
    const size_t o_st   = o_ysm  + (size_t)Bsz * KK * LL * DI;

    float* xx    = ws + o_xx;
    float* zs    = ws + o_zs;
    float* xxT   = ws + o_xxT;
    float* xdbl  = ws + o_xdbl;
    float* Pst   = ws + o_P;
    float* Hst   = ws + o_H;
    float* ysm   = ws + o_ysm;
    float* stats = ws + o_st;
    float* ym = xx;    // xx dead after convT

    hipLaunchKernelGGL(in_proj_k, dim3(768), dim3(256), 0, stream, x, ipw, xx, zs, stats);
    hipLaunchKernelGGL(convT_k, dim3(384), dim3(256), 0, stream, xx, cw, cb, xxT);
    hipLaunchKernelGGL(xdbl_k, dim3(256), dim3(512), 0, stream, xxT, xpw, xdbl);

    void* ka[] = {(void*)&xxT, (void*)&xdbl, (void*)&dtw, (void*)&dtb,
                  (void*)&Alog, (void*)&Ds, (void*)&Pst, (void*)&Hst, (void*)&ysm};
    hipLaunchCooperativeKernel((const void*)megascan_k, dim3(Bsz * KK * NC), dim3(192),
                               ka, 0, stream);

    hipLaunchKernelGGL(merge_k, dim3(LL / MT, Bsz), dim3(192), 0, stream, ysm, ym, stats);
    hipLaunchKernelGGL(outz_k, dim3(384), dim3(256), 0, stream, ym, zs, gng, gnb, stats, opw, out);
}

// Round 3
// 232.875 us; speedup vs baseline: 1.9303x; 1.9303x over previous
//
#include <hip/hip_runtime.h>
#include <math.h>

#define Bsz 4
#define DM 96
#define DI 192
#define NS 16
#define RK 6
#define KK 4
#define HH 32
#define WW 32
#define LL 1024
#define NC 32          // chunks along L
#define CS 32          // chunk size (NC*CS == LL)

__device__ __forceinline__ float silu_f(float x) { return x / (1.f + __expf(-x)); }

// forward snake map: scan position l -> flat spatial index hw for direction k
__device__ __forceinline__ int hw_of_l(int k, int l) {
    int a = l >> 5, r = l & 31;
    int m = (a & 1) ? 31 - r : r;
    int h, w;
    if (k < 2) { w = a; h = m; }      // vertical snake
    else       { h = a; w = m; }      // horizontal snake
    if (k & 1) { h = 31 - h; w = 31 - w; }
    return h * 32 + w;
}

// ---- in_proj: 8 outputs per thread; also zeroes stats ---------------------
__global__ void in_proj_k(const float* __restrict__ x, const float* __restrict__ w,
                          float* __restrict__ xx, float* __restrict__ zs,
                          float* __restrict__ stats) {
    int bi = blockIdx.x;                 // 4 lblk * 48 og * 4 b
    int t = threadIdx.x;
    if (bi == 0 && t < 2 * Bsz) stats[t] = 0.f;
    int lb = bi & 3;
    int og = (bi >> 2) % 48;
    int b = bi / 192;
    int l = lb * 256 + t;
    const float* xb = x + (size_t)b * DM * LL + l;
    float acc[8];
#pragma unroll
    for (int g = 0; g < 8; g++) acc[g] = 0.f;
    for (int c = 0; c < DM; c++) {
        float xv = xb[(size_t)c * LL];
#pragma unroll
        for (int g = 0; g < 8; g++)
            acc[g] = fmaf(xv, w[(size_t)(og * 8 + g) * DM + c], acc[g]);
    }
#pragma unroll
    for (int g = 0; g < 8; g++) {
        int o = og * 8 + g;
        if (o < DI) xx[((size_t)b * DI + o) * LL + l] = acc[g];
        else        zs[((size_t)b * DI + (o - DI)) * LL + l] = silu_f(acc[g]);
    }
}

// ---- depthwise conv3x3+silu -> transposed layout xxT[b][hw][d] ------------
__global__ void convT_k(const float* __restrict__ xx, const float* __restrict__ cw,
                        const float* __restrict__ cb, float* __restrict__ xxT) {
    __shared__ float tile[32][65];
    int bi = blockIdx.x;                 // 32 rows * 3 dtiles * 4 b
    int h0 = bi % 32;
    int dt = (bi / 32) % 3;
    int b = bi / 96;
    int d0 = dt * 64;
    int t = threadIdx.x;
    int wi = t & 31, dg = t >> 5;

#pragma unroll
    for (int pass = 0; pass < 8; pass++) {
        int di = pass * 8 + dg;
        int d = d0 + di;
        const float* xp = xx + ((size_t)b * DI + d) * LL;
        const float* wp = cw + d * 9;
        float acc = cb[d];
#pragma unroll
        for (int kh = 0; kh < 3; kh++) {
            int hh = h0 + kh - 1;
            if (hh < 0 || hh >= HH) continue;
#pragma unroll
            for (int kw = 0; kw < 3; kw++) {
                int ww2 = wi + kw - 1;
                if (ww2 < 0 || ww2 >= WW) continue;
                acc = fmaf(xp[hh * WW + ww2], wp[kh * 3 + kw], acc);
            }
        }
        tile[wi][di] = silu_f(acc);
    }
    __syncthreads();

    int di = t & 63, w4 = t >> 6;
#pragma unroll
    for (int rep = 0; rep < 8; rep++) {
        int w2 = rep * 4 + w4;
        xxT[((size_t)b * LL + h0 * 32 + w2) * DI + d0 + di] = tile[w2][di];
    }
}

// ---- x_dbl: tiled GEMM; stage 64 gathered rows of xxT, output [bk][l][38] -
__global__ void __launch_bounds__(512)
xdbl_k(const float* __restrict__ xxT, const float* __restrict__ xpw,
       float* __restrict__ xdbl) {
    __shared__ float tile[64 * 193];
    int blk = blockIdx.x;            // bk*16 + lt
    int bk = blk >> 4, lt = blk & 15;
    int k = bk & 3, b = bk >> 2;
    int t = threadIdx.x;

    const float* xb = xxT + (size_t)b * LL * DI;
#pragma unroll
    for (int i = 0; i < 6; i++) {
        int j4 = t + i * 512;
        int lr = j4 / 48;            // 48 float4 per row
        int d4 = j4 % 48;
        int hw = hw_of_l(k, lt * 64 + lr);
        float4 v = ((const float4*)(xb + (size_t)hw * DI))[d4];
        float* dst = &tile[lr * 193 + d4 * 4];
        dst[0] = v.x; dst[1] = v.y; dst[2] = v.z; dst[3] = v.w;
    }
    __syncthreads();

    int ll = t & 63;                 // lane -> l (2-way bank = free)
    int cg = t >> 6;                 // wave-uniform c-group 0..7
    int c0 = cg * 5;
    int wlim = (c0 + 5 <= 38) ? 5 : (38 - c0);   // 5,...,5,3
    const float* wk = xpw + (size_t)k * 38 * DI;

    float acc[5];
#pragma unroll
    for (int j = 0; j < 5; j++) acc[j] = 0.f;
    const float* xrow = &tile[ll * 193];
#pragma unroll 4
    for (int d = 0; d < DI; d++) {
        float xv = xrow[d];
#pragma unroll
        for (int j = 0; j < 5; j++) {
            int cc = c0 + j; cc = (cc > 37) ? 37 : cc;
            acc[j] = fmaf(xv, wk[(size_t)cc * DI + d], acc[j]);
        }
    }
    float* orow = xdbl + ((size_t)bk * LL + lt * 64 + ll) * 38;
#pragma unroll
    for (int j = 0; j < 5; j++)
        if (j < wlim) orow[c0 + j] = acc[j];
}

// ---- scan phase 1: per-chunk local scan, write (P, Hloc) summaries --------
__global__ void scan_p1(const float* __restrict__ xxT, const float* __restrict__ xdbl,
                        const float* __restrict__ dtw_g, const float* __restrict__ dtb_g,
                        const float* __restrict__ Alog,
                        float* __restrict__ Pst, float* __restrict__ Hloc) {
    int blk = blockIdx.x;           // bk*NC + c
    int bk = blk / NC, c = blk % NC;
    int k = bk & 3, b = bk >> 2;
    int d = threadIdx.x;
    int kd = k * DI + d;

    float A[NS];
#pragma unroll
    for (int n = 0; n < NS; n++) A[n] = -__expf(Alog[(size_t)kd * NS + n]);
    float dtw[RK];
#pragma unroll
    for (int r = 0; r < RK; r++) dtw[r] = dtw_g[(size_t)kd * RK + r];
    float dtb = dtb_g[kd];

    float h[NS], P[NS];
#pragma unroll
    for (int n = 0; n < NS; n++) { h[n] = 0.f; P[n] = 1.f; }

    const float* xdbase = xdbl + ((size_t)bk * LL + c * CS) * 38;
    const float* xb = xxT + (size_t)b * LL * DI;

    for (int s = 0; s < CS; s++) {
        const float* xd = xdbase + s * 38;
        int hw = hw_of_l(k, c * CS + s);
        float u = xb[(size_t)hw * DI + d];
        float dt = dtb;
#pragma unroll
        for (int r = 0; r < RK; r++) dt = fmaf(xd[r], dtw[r], dt);
        dt = (dt > 20.f) ? dt : __logf(1.f + __expf(dt));
        float du = dt * u;
#pragma unroll
        for (int n = 0; n < NS; n++) {
            float a = __expf(dt * A[n]);
            h[n] = fmaf(a, h[n], du * xd[6 + n]);
            P[n] *= a;
        }
    }
    if (c < NC - 1) {   // last chunk's summary is never consumed
        size_t base = ((size_t)blk * DI + d) * NS;
#pragma unroll
        for (int n = 0; n < NS; n++) { Pst[base + n] = P[n]; Hloc[base + n] = h[n]; }
    }
}

// ---- scan phase 2+3: self-computed prefix, then final scan + y ------------
// Block (bk,c) folds the c preceding chunk summaries (coalesced L2 reads,
// ILP-16 fma chain), then runs the final recurrence and writes y at spatial
// positions. Replaces scan_mid + scan_p3 without any grid sync.
__global__ void scan_p23(const float* __restrict__ xxT, const float* __restrict__ xdbl,
                         const float* __restrict__ dtw_g, const float* __restrict__ dtb_g,
                         const float* __restrict__ Alog, const float* __restrict__ Ds,
                         const float* __restrict__ Pst, const float* __restrict__ Hloc,
                         float* __restrict__ ysm) {
    int blk = blockIdx.x;
    int bk = blk / NC, c = blk % NC;
    int k = bk & 3, b = bk >> 2;
    int d = threadIdx.x;
    int kd = k * DI + d;

    float A[NS];
#pragma unroll
    for (int n = 0; n < NS; n++) A[n] = -__expf(Alog[(size_t)kd * NS + n]);
    float dtw[RK];
#pragma unroll
    for (int r = 0; r < RK; r++) dtw[r] = dtw_g[(size_t)kd * RK + r];
    float dtb = dtb_g[kd];
    float Dp = Ds[kd];

    // prefix over preceding chunks: h = P_cc * h + H_cc, cc ascending
    float h[NS];
#pragma unroll
    for (int n = 0; n < NS; n++) h[n] = 0.f;
    for (int cc = 0; cc < c; cc++) {
        size_t a = (((size_t)bk * NC + cc) * DI + d) * NS;
#pragma unroll
        for (int n = 0; n < NS; n++) {
            float p  = Pst[a + n];
            float hl = Hloc[a + n];
            h[n] = fmaf(p, h[n], hl);
        }
    }

    const float* xdbase = xdbl + ((size_t)bk * LL + c * CS) * 38;
    const float* xb = xxT + (size_t)b * LL * DI;
    float* yk = ysm + (size_t)bk * LL * DI;

    for (int s = 0; s < CS; s++) {
        const float* xd = xdbase + s * 38;
        int hw = hw_of_l(k, c * CS + s);
        float u = xb[(size_t)hw * DI + d];
        float dt = dtb;
#pragma unroll
        for (int r = 0; r < RK; r++) dt = fmaf(xd[r], dtw[r], dt);
        dt = (dt > 20.f) ? dt : __logf(1.f + __expf(dt));
        float du = dt * u;
        float y = 0.f;
#pragma unroll
        for (int n = 0; n < NS; n++) {
            float a = __expf(dt * A[n]);
            h[n] = fmaf(a, h[n], du * xd[6 + n]);
            y = fmaf(h[n], xd[22 + n], y);
        }
        yk[(size_t)hw * DI + d] = fmaf(Dp, u, y);   // write at spatial position
    }
}

// ---- cross-merge: sequential reads (ysm is hw-ordered), stats -------------
#define MT 16
__global__ void merge_k(const float* __restrict__ ysm, float* __restrict__ ym,
                        float* __restrict__ stats) {
    __shared__ float tile[MT][DI + 1];
    __shared__ float sh1[3], sh2[3];
    int b = blockIdx.y;
    int hw0 = blockIdx.x * MT;
    int d = threadIdx.x;
    const float* yb = ysm + (size_t)b * KK * LL * DI;

    float s1 = 0.f, s2 = 0.f;
#pragma unroll
    for (int hwi = 0; hwi < MT; hwi++) {
        int hw = hw0 + hwi;
        float v = yb[((size_t)0 * LL + hw) * DI + d]
                + yb[((size_t)1 * LL + hw) * DI + d]
                + yb[((size_t)2 * LL + hw) * DI + d]
                + yb[((size_t)3 * LL + hw) * DI + d];
        tile[hwi][d] = v;
        s1 += v; s2 = fmaf(v, v, s2);
    }
#pragma unroll
    for (int off = 32; off > 0; off >>= 1) {
        s1 += __shfl_down(s1, off);
        s2 += __shfl_down(s2, off);
    }
    int lane = threadIdx.x & 63, wid = threadIdx.x >> 6;
    if (lane == 0) { sh1[wid] = s1; sh2[wid] = s2; }
    __syncthreads();
    if (threadIdx.x == 0) {
        atomicAdd(&stats[b * 2],     sh1[0] + sh1[1] + sh1[2]);
        atomicAdd(&stats[b * 2 + 1], sh2[0] + sh2[1] + sh2[2]);
    }
#pragma unroll
    for (int rep = 0; rep < MT; rep++) {
        int j = rep * DI + threadIdx.x;
        int d2 = j >> 4;
        int hwi = j & (MT - 1);
        ym[((size_t)b * DI + d2) * LL + hw0 + hwi] = tile[hwi][d2];
    }
}

// ---- fused norm + gate + out projection -----------------------------------
__global__ void outz_k(const float* __restrict__ ym, const float* __restrict__ zs,
                       const float* __restrict__ g, const float* __restrict__ be,
                       const float* __restrict__ stats, const float* __restrict__ wo,
                       float* __restrict__ out) {
    int bi = blockIdx.x;                 // 4 lblk * 24 og * 4 b
    int t = threadIdx.x;
    int lb = bi & 3;
    int og = (bi >> 2) % 24;
    int b = bi / 96;
    int l = lb * 256 + t;

    const float Ninv = 1.f / (float)(DI * LL);
    float mu = stats[b * 2] * Ninv;
    float var = stats[b * 2 + 1] * Ninv - mu * mu;
    float rstd = rsqrtf(var + 1e-6f);

    const float* yb = ym + (size_t)b * DI * LL + l;
    const float* zb = zs + (size_t)b * DI * LL + l;
    float acc[4];
#pragma unroll
    for (int gg = 0; gg < 4; gg++) acc[gg] = 0.f;
    for (int c = 0; c < DI; c++) {
        float v = (yb[(size_t)c * LL] - mu) * rstd * g[c] + be[c];
        float yv = v * zb[(size_t)c * LL];
#pragma unroll
        for (int gg = 0; gg < 4; gg++)
            acc[gg] = fmaf(yv, wo[(size_t)(og * 4 + gg) * DI + c], acc[gg]);
    }
#pragma unroll
    for (int gg = 0; gg < 4; gg++)
        out[((size_t)b * DM + og * 4 + gg) * LL + l] = acc[gg];
}

extern "C" void kernel_launch(void* const* d_in, const int* in_sizes, int n_in,
                              void* d_out, int out_size, void* d_ws, size_t ws_size,
                              hipStream_t stream) {
    const float* x    = (const float*)d_in[0];
    const float* ipw  = (const float*)d_in[1];
    const float* cw   = (const float*)d_in[2];
    const float* cb   = (const float*)d_in[3];
    const float* xpw  = (const float*)d_in[4];
    const float* dtw  = (const float*)d_in[5];
    const float* dtb  = (const float*)d_in[6];
    const float* Alog = (const float*)d_in[7];
    const float* Ds   = (const float*)d_in[8];
    const float* gng  = (const float*)d_in[9];
    const float* gnb  = (const float*)d_in[10];
    const float* opw  = (const float*)d_in[11];
    float* out = (float*)d_out;

    float* ws = (float*)d_ws;
    const size_t o_xx   = 0;                                       // (→ ym)
    const size_t o_zs   = o_xx   + (size_t)Bsz * DI * LL;
    const size_t o_xxT  = o_zs   + (size_t)Bsz * DI * LL;
    const size_t o_xdbl = o_xxT  + (size_t)Bsz * LL * DI;
    const size_t o_P    = o_xdbl + (size_t)Bsz * KK * LL * 38;
    const size_t o_H    = o_P    + (size_t)Bsz * KK * NC * DI * NS;
    const size_t o_ysm  = o_H    + (size_t)Bsz * KK * NC * DI * NS;
    const size_t o_st   = o_ysm  + (size_t)Bsz * KK * LL * DI;

    float* xx    = ws + o_xx;
    float* zs    = ws + o_zs;
    float* xxT   = ws + o_xxT;
    float* xdbl  = ws + o_xdbl;
    float* Pst   = ws + o_P;
    float* Hst   = ws + o_H;
    float* ysm   = ws + o_ysm;
    float* stats = ws + o_st;
    float* ym = xx;    // xx dead after convT

    hipLaunchKernelGGL(in_proj_k, dim3(768), dim3(256), 0, stream, x, ipw, xx, zs, stats);
    hipLaunchKernelGGL(convT_k, dim3(384), dim3(256), 0, stream, xx, cw, cb, xxT);
    hipLaunchKernelGGL(xdbl_k, dim3(256), dim3(512), 0, stream, xxT, xpw, xdbl);
    hipLaunchKernelGGL(scan_p1, dim3(Bsz * KK * NC), dim3(192), 0, stream,
                       xxT, xdbl, dtw, dtb, Alog, Pst, Hst);
    hipLaunchKernelGGL(scan_p23, dim3(Bsz * KK * NC), dim3(192), 0, stream,
                       xxT, xdbl, dtw, dtb, Alog, Ds, Pst, Hst, ysm);
    hipLaunchKernelGGL(merge_k, dim3(LL / MT, Bsz), dim3(192), 0, stream, ysm, ym, stats);
    hipLaunchKernelGGL(outz_k, dim3(384), dim3(256), 0, stream, ym, zs, gng, gnb, stats, opw, out);
}

// Round 4
// 219.535 us; speedup vs baseline: 2.0476x; 1.0608x over previous
//
#include <hip/hip_runtime.h>
#include <math.h>

#define Bsz 4
#define DM 96
#define DI 192
#define NS 16
#define RK 6
#define KK 4
#define HH 32
#define WW 32
#define LL 1024
#define NC 64          // chunks along L
#define CS 16          // chunk size (NC*CS == LL)

__device__ __forceinline__ float silu_f(float x) { return x / (1.f + __expf(-x)); }

// forward snake map: scan position l -> flat spatial index hw for direction k
__device__ __forceinline__ int hw_of_l(int k, int l) {
    int a = l >> 5, r = l & 31;
    int m = (a & 1) ? 31 - r : r;
    int h, w;
    if (k < 2) { w = a; h = m; }      // vertical snake
    else       { h = a; w = m; }      // horizontal snake
    if (k & 1) { h = 31 - h; w = 31 - w; }
    return h * 32 + w;
}

// ---- in_proj: 4 outputs per thread (1536 blocks, 6 blk/CU); zeroes stats --
__global__ void in_proj_k(const float* __restrict__ x, const float* __restrict__ w,
                          float* __restrict__ xx, float* __restrict__ zs,
                          float* __restrict__ stats) {
    int bi = blockIdx.x;                 // 4 lblk * 96 og * 4 b
    int t = threadIdx.x;
    if (bi == 0 && t < 2 * Bsz) stats[t] = 0.f;
    int lb = bi & 3;
    int og = (bi >> 2) % 96;
    int b = bi / 384;
    int l = lb * 256 + t;
    const float* xb = x + (size_t)b * DM * LL + l;
    float acc[4];
#pragma unroll
    for (int g = 0; g < 4; g++) acc[g] = 0.f;
    for (int c = 0; c < DM; c++) {
        float xv = xb[(size_t)c * LL];
#pragma unroll
        for (int g = 0; g < 4; g++)
            acc[g] = fmaf(xv, w[(size_t)(og * 4 + g) * DM + c], acc[g]);
    }
#pragma unroll
    for (int g = 0; g < 4; g++) {
        int o = og * 4 + g;
        if (o < DI) xx[((size_t)b * DI + o) * LL + l] = acc[g];
        else        zs[((size_t)b * DI + (o - DI)) * LL + l] = silu_f(acc[g]);
    }
}

// ---- depthwise conv3x3+silu -> xxT[b][hw][d]; 32-wide d tiles (768 blocks)
__global__ void convT_k(const float* __restrict__ xx, const float* __restrict__ cw,
                        const float* __restrict__ cb, float* __restrict__ xxT) {
    __shared__ float tile[32][33];
    int bi = blockIdx.x;                 // 32 rows * 6 dtiles * 4 b
    int h0 = bi % 32;
    int dt = (bi / 32) % 6;
    int b = bi / 192;
    int d0 = dt * 32;
    int t = threadIdx.x;
    int wi = t & 31, dg = t >> 5;

#pragma unroll
    for (int pass = 0; pass < 4; pass++) {
        int di = pass * 8 + dg;
        int d = d0 + di;
        const float* xp = xx + ((size_t)b * DI + d) * LL;
        const float* wp = cw + d * 9;
        float acc = cb[d];
#pragma unroll
        for (int kh = 0; kh < 3; kh++) {
            int hh = h0 + kh - 1;
            if (hh < 0 || hh >= HH) continue;
#pragma unroll
            for (int kw = 0; kw < 3; kw++) {
                int ww2 = wi + kw - 1;
                if (ww2 < 0 || ww2 >= WW) continue;
                acc = fmaf(xp[hh * WW + ww2], wp[kh * 3 + kw], acc);
            }
        }
        tile[wi][di] = silu_f(acc);
    }
    __syncthreads();

    int di = t & 31, w8 = t >> 5;
#pragma unroll
    for (int rep = 0; rep < 4; rep++) {
        int w2 = rep * 8 + w8;
        xxT[((size_t)b * LL + h0 * 32 + w2) * DI + d0 + di] = tile[w2][di];
    }
}

// ---- x_dbl: tiled GEMM; stage 64 gathered rows of xxT, output [bk][l][38] -
__global__ void __launch_bounds__(512)
xdbl_k(const float* __restrict__ xxT, const float* __restrict__ xpw,
       float* __restrict__ xdbl) {
    __shared__ float tile[64 * 193];
    int blk = blockIdx.x;            // bk*16 + lt
    int bk = blk >> 4, lt = blk & 15;
    int k = bk & 3, b = bk >> 2;
    int t = threadIdx.x;

    const float* xb = xxT + (size_t)b * LL * DI;
#pragma unroll
    for (int i = 0; i < 6; i++) {
        int j4 = t + i * 512;
        int lr = j4 / 48;            // 48 float4 per row
        int d4 = j4 % 48;
        int hw = hw_of_l(k, lt * 64 + lr);
        float4 v = ((const float4*)(xb + (size_t)hw * DI))[d4];
        float* dst = &tile[lr * 193 + d4 * 4];
        dst[0] = v.x; dst[1] = v.y; dst[2] = v.z; dst[3] = v.w;
    }
    __syncthreads();

    int ll = t & 63;                 // lane -> l (2-way bank = free)
    int cg = t >> 6;                 // wave-uniform c-group 0..7
    int c0 = cg * 5;
    int wlim = (c0 + 5 <= 38) ? 5 : (38 - c0);   // 5,...,5,3
    const float* wk = xpw + (size_t)k * 38 * DI;

    float acc[5];
#pragma unroll
    for (int j = 0; j < 5; j++) acc[j] = 0.f;
    const float* xrow = &tile[ll * 193];
#pragma unroll 4
    for (int d = 0; d < DI; d++) {
        float xv = xrow[d];
#pragma unroll
        for (int j = 0; j < 5; j++) {
            int cc = c0 + j; cc = (cc > 37) ? 37 : cc;
            acc[j] = fmaf(xv, wk[(size_t)cc * DI + d], acc[j]);
        }
    }
    float* orow = xdbl + ((size_t)bk * LL + lt * 64 + ll) * 38;
#pragma unroll
    for (int j = 0; j < 5; j++)
        if (j < wlim) orow[c0 + j] = acc[j];
}

// ---- scan phase 1: per-chunk local scan, (P, Hloc) summaries --------------
__global__ void scan_p1(const float* __restrict__ xxT, const float* __restrict__ xdbl,
                        const float* __restrict__ dtw_g, const float* __restrict__ dtb_g,
                        const float* __restrict__ Alog,
                        float* __restrict__ Pst, float* __restrict__ Hloc) {
    __shared__ float xd_tile[CS * 38];
    int blk = blockIdx.x;           // bk*NC + c
    int bk = blk / NC, c = blk % NC;
    int k = bk & 3, b = bk >> 2;
    int t = threadIdx.x;

    const float* xdsrc = xdbl + ((size_t)bk * LL + c * CS) * 38;
    for (int i = t; i < CS * 38; i += 192) xd_tile[i] = xdsrc[i];
    __syncthreads();

    int d = t;
    int kd = k * DI + d;

    float A[NS];
#pragma unroll
    for (int n = 0; n < NS; n++) A[n] = -__expf(Alog[(size_t)kd * NS + n]);
    float dtw[RK];
#pragma unroll
    for (int r = 0; r < RK; r++) dtw[r] = dtw_g[(size_t)kd * RK + r];
    float dtb = dtb_g[kd];

    float h[NS], P[NS];
#pragma unroll
    for (int n = 0; n < NS; n++) { h[n] = 0.f; P[n] = 1.f; }

    const float* xb = xxT + (size_t)b * LL * DI;

    for (int s = 0; s < CS; s++) {
        const float* xd = &xd_tile[s * 38];
        int hw = hw_of_l(k, c * CS + s);
        float u = xb[(size_t)hw * DI + d];
        float dt = dtb;
#pragma unroll
        for (int r = 0; r < RK; r++) dt = fmaf(xd[r], dtw[r], dt);
        dt = (dt > 20.f) ? dt : __logf(1.f + __expf(dt));
        float du = dt * u;
#pragma unroll
        for (int n = 0; n < NS; n++) {
            float a = __expf(dt * A[n]);
            h[n] = fmaf(a, h[n], du * xd[6 + n]);
            P[n] *= a;
        }
    }
    size_t base = ((size_t)blk * DI + d) * NS;
#pragma unroll
    for (int n = 0; n < NS; n++) { Pst[base + n] = P[n]; Hloc[base + n] = h[n]; }
}

// ---- middle compose: 2 chains/thread (float2), depth-4 prefetch -----------
__global__ void scan_mid(const float* __restrict__ Pst, float* __restrict__ Hloc) {
    int gid = blockIdx.x * 256 + threadIdx.x;     // bk*1536 + j  (j = float2 idx)
    int bk = gid / 1536;
    int j = gid % 1536;
    const float2* Pp = (const float2*)(Pst + (size_t)bk * NC * (DI * NS)) + j;
    float2* Hp = (float2*)(Hloc + (size_t)bk * NC * (DI * NS)) + j;
    const int S = (DI * NS) / 2;     // stride between chunks in float2

    float2 h = make_float2(0.f, 0.f);
    float2 P[4], L[4];
#pragma unroll
    for (int q = 0; q < 4; q++) { P[q] = Pp[(size_t)q * S]; L[q] = Hp[(size_t)q * S]; }
    for (int c = 0; c < NC; c += 4) {
        float2 Pn[4], Ln[4];
        if (c + 4 < NC) {
#pragma unroll
            for (int q = 0; q < 4; q++) {
                Pn[q] = Pp[(size_t)(c + 4 + q) * S];
                Ln[q] = Hp[(size_t)(c + 4 + q) * S];
            }
        }
#pragma unroll
        for (int q = 0; q < 4; q++) {
            Hp[(size_t)(c + q) * S] = h;
            h.x = fmaf(P[q].x, h.x, L[q].x);
            h.y = fmaf(P[q].y, h.y, L[q].y);
        }
#pragma unroll
        for (int q = 0; q < 4; q++) { P[q] = Pn[q]; L[q] = Ln[q]; }
    }
}

// ---- scan phase 3: final scan from prefix, write y at spatial positions ---
__global__ void scan_p3(const float* __restrict__ xxT, const float* __restrict__ xdbl,
                        const float* __restrict__ dtw_g, const float* __restrict__ dtb_g,
                        const float* __restrict__ Alog, const float* __restrict__ Ds,
                        const float* __restrict__ Hin, float* __restrict__ ysm) {
    __shared__ float xd_tile[CS * 38];
    int blk = blockIdx.x;
    int bk = blk / NC, c = blk % NC;
    int k = bk & 3, b = bk >> 2;
    int t = threadIdx.x;

    const float* xdsrc = xdbl + ((size_t)bk * LL + c * CS) * 38;
    for (int i = t; i < CS * 38; i += 192) xd_tile[i] = xdsrc[i];
    __syncthreads();

    int d = t;
    int kd = k * DI + d;

    float A[NS];
#pragma unroll
    for (int n = 0; n < NS; n++) A[n] = -__expf(Alog[(size_t)kd * NS + n]);
    float dtw[RK];
#pragma unroll
    for (int r = 0; r < RK; r++) dtw[r] = dtw_g[(size_t)kd * RK + r];
    float dtb = dtb_g[kd];
    float Dp = Ds[kd];

    float h[NS];
    size_t hbase = ((size_t)blk * DI + d) * NS;
#pragma unroll
    for (int n = 0; n < NS; n++) h[n] = Hin[hbase + n];

    const float* xb = xxT + (size_t)b * LL * DI;
    float* yk = ysm + (size_t)bk * LL * DI;

    for (int s = 0; s < CS; s++) {
        const float* xd = &xd_tile[s * 38];
        int hw = hw_of_l(k, c * CS + s);
        float u = xb[(size_t)hw * DI + d];
        float dt = dtb;
#pragma unroll
        for (int r = 0; r < RK; r++) dt = fmaf(xd[r], dtw[r], dt);
        dt = (dt > 20.f) ? dt : __logf(1.f + __expf(dt));
        float du = dt * u;
        float y = 0.f;
#pragma unroll
        for (int n = 0; n < NS; n++) {
            float a = __expf(dt * A[n]);
            h[n] = fmaf(a, h[n], du * xd[6 + n]);
            y = fmaf(h[n], xd[22 + n], y);
        }
        yk[(size_t)hw * DI + d] = fmaf(Dp, u, y);   // write at spatial position
    }
}

// ---- cross-merge: MT=4 -> 1024 blocks, sequential reads, stats ------------
#define MT 4
__global__ void merge_k(const float* __restrict__ ysm, float* __restrict__ ym,
                        float* __restrict__ stats) {
    __shared__ float tile[MT][DI + 1];
    __shared__ float sh1[3], sh2[3];
    int b = blockIdx.y;
    int hw0 = blockIdx.x * MT;
    int d = threadIdx.x;
    const float* yb = ysm + (size_t)b * KK * LL * DI;

    float s1 = 0.f, s2 = 0.f;
#pragma unroll
    for (int hwi = 0; hwi < MT; hwi++) {
        int hw = hw0 + hwi;
        float v = yb[((size_t)0 * LL + hw) * DI + d]
                + yb[((size_t)1 * LL + hw) * DI + d]
                + yb[((size_t)2 * LL + hw) * DI + d]
                + yb[((size_t)3 * LL + hw) * DI + d];
        tile[hwi][d] = v;
        s1 += v; s2 = fmaf(v, v, s2);
    }
#pragma unroll
    for (int off = 32; off > 0; off >>= 1) {
        s1 += __shfl_down(s1, off);
        s2 += __shfl_down(s2, off);
    }
    int lane = threadIdx.x & 63, wid = threadIdx.x >> 6;
    if (lane == 0) { sh1[wid] = s1; sh2[wid] = s2; }
    __syncthreads();
    if (threadIdx.x == 0) {
        atomicAdd(&stats[b * 2],     sh1[0] + sh1[1] + sh1[2]);
        atomicAdd(&stats[b * 2 + 1], sh2[0] + sh2[1] + sh2[2]);
    }
#pragma unroll
    for (int rep = 0; rep < MT; rep++) {
        int j = rep * DI + threadIdx.x;
        int d2 = j >> 2;            // j / MT
        int hwi = j & (MT - 1);
        ym[((size_t)b * DI + d2) * LL + hw0 + hwi] = tile[hwi][d2];
    }
}

// ---- fused norm + gate + out projection: 3 outputs/thread (512 blocks) ----
__global__ void outz_k(const float* __restrict__ ym, const float* __restrict__ zs,
                       const float* __restrict__ g, const float* __restrict__ be,
                       const float* __restrict__ stats, const float* __restrict__ wo,
                       float* __restrict__ out) {
    int bi = blockIdx.x;                 // 4 lblk * 32 og * 4 b
    int t = threadIdx.x;
    int lb = bi & 3;
    int og = (bi >> 2) % 32;
    int b = bi / 128;
    int l = lb * 256 + t;

    const float Ninv = 1.f / (float)(DI * LL);
    float mu = stats[b * 2] * Ninv;
    float var = stats[b * 2 + 1] * Ninv - mu * mu;
    float rstd = rsqrtf(var + 1e-6f);

    const float* yb = ym + (size_t)b * DI * LL + l;
    const float* zb = zs + (size_t)b * DI * LL + l;
    float acc[3];
#pragma unroll
    for (int gg = 0; gg < 3; gg++) acc[gg] = 0.f;
    for (int c = 0; c < DI; c++) {
        float v = (yb[(size_t)c * LL] - mu) * rstd * g[c] + be[c];
        float yv = v * zb[(size_t)c * LL];
#pragma unroll
        for (int gg = 0; gg < 3; gg++)
            acc[gg] = fmaf(yv, wo[(size_t)(og * 3 + gg) * DI + c], acc[gg]);
    }
#pragma unroll
    for (int gg = 0; gg < 3; gg++)
        out[((size_t)b * DM + og * 3 + gg) * LL + l] = acc[gg];
}

extern "C" void kernel_launch(void* const* d_in, const int* in_sizes, int n_in,
                              void* d_out, int out_size, void* d_ws, size_t ws_size,
                              hipStream_t stream) {
    const float* x    = (const float*)d_in[0];
    const float* ipw  = (const float*)d_in[1];
    const float* cw   = (const float*)d_in[2];
    const float* cb   = (const float*)d_in[3];
    const float* xpw  = (const float*)d_in[4];
    const float* dtw  = (const float*)d_in[5];
    const float* dtb  = (const float*)d_in[6];
    const float* Alog = (const float*)d_in[7];
    const float* Ds   = (const float*)d_in[8];
    const float* gng  = (const float*)d_in[9];
    const float* gnb  = (const float*)d_in[10];
    const float* opw  = (const float*)d_in[11];
    float* out = (float*)d_out;

    float* ws = (float*)d_ws;
    const size_t o_xx   = 0;                                       // (→ ym)
    const size_t o_zs   = o_xx   + (size_t)Bsz * DI * LL;
    const size_t o_xxT  = o_zs   + (size_t)Bsz * DI * LL;
    const size_t o_xdbl = o_xxT  + (size_t)Bsz * LL * DI;
    const size_t o_P    = o_xdbl + (size_t)Bsz * KK * LL * 38;
    const size_t o_H    = o_P    + (size_t)Bsz * KK * NC * DI * NS;
    const size_t o_ysm  = o_H    + (size_t)Bsz * KK * NC * DI * NS;
    const size_t o_st   = o_ysm  + (size_t)Bsz * KK * LL * DI;

    float* xx    = ws + o_xx;
    float* zs    = ws + o_zs;
    float* xxT   = ws + o_xxT;
    float* xdbl  = ws + o_xdbl;
    float* Pst   = ws + o_P;
    float* Hst   = ws + o_H;
    float* ysm   = ws + o_ysm;
    float* stats = ws + o_st;
    float* ym = xx;    // xx dead after convT

    hipLaunchKernelGGL(in_proj_k, dim3(1536), dim3(256), 0, stream, x, ipw, xx, zs, stats);
    hipLaunchKernelGGL(convT_k, dim3(768), dim3(256), 0, stream, xx, cw, cb, xxT);
    hipLaunchKernelGGL(xdbl_k, dim3(256), dim3(512), 0, stream, xxT, xpw, xdbl);
    hipLaunchKernelGGL(scan_p1, dim3(Bsz * KK * NC), dim3(192), 0, stream,
                       xxT, xdbl, dtw, dtb, Alog, Pst, Hst);
    hipLaunchKernelGGL(scan_mid, dim3(96), dim3(256), 0, stream, Pst, Hst);
    hipLaunchKernelGGL(scan_p3, dim3(Bsz * KK * NC), dim3(192), 0, stream,
                       xxT, xdbl, dtw, dtb, Alog, Ds, Hst, ysm);
    hipLaunchKernelGGL(merge_k, dim3(LL / MT, Bsz), dim3(192), 0, stream, ysm, ym, stats);
    hipLaunchKernelGGL(outz_k, dim3(512), dim3(256), 0, stream, ym, zs, gng, gnb, stats, opw, out);
}

// Round 5
// 206.987 us; speedup vs baseline: 2.1718x; 1.0606x over previous
//
#include <hip/hip_runtime.h>
#include <math.h>

#define Bsz 4
#define DM 96
#define DI 192
#define NS 16
#define RK 6
#define KK 4
#define HH 32
#define WW 32
#define LL 1024
#define NC 32          // chunks along L
#define CS 32          // chunk size (NC*CS == LL)

__device__ __forceinline__ float silu_f(float x) { return x / (1.f + __expf(-x)); }

// forward snake map: scan position l -> flat spatial index hw for direction k
__device__ __forceinline__ int hw_of_l(int k, int l) {
    int a = l >> 5, r = l & 31;
    int m = (a & 1) ? 31 - r : r;
    int h, w;
    if (k < 2) { w = a; h = m; }      // vertical snake
    else       { h = a; w = m; }      // horizontal snake
    if (k & 1) { h = 31 - h; w = 31 - w; }
    return h * 32 + w;
}

// ---- in_proj: 4 outputs per thread (1536 blocks, 6 blk/CU); zeroes stats --
__global__ void in_proj_k(const float* __restrict__ x, const float* __restrict__ w,
                          float* __restrict__ xx, float* __restrict__ zs,
                          float* __restrict__ stats) {
    int bi = blockIdx.x;                 // 4 lblk * 96 og * 4 b
    int t = threadIdx.x;
    if (bi == 0 && t < 2 * Bsz) stats[t] = 0.f;
    int lb = bi & 3;
    int og = (bi >> 2) % 96;
    int b = bi / 384;
    int l = lb * 256 + t;
    const float* xb = x + (size_t)b * DM * LL + l;
    float acc[4];
#pragma unroll
    for (int g = 0; g < 4; g++) acc[g] = 0.f;
    for (int c = 0; c < DM; c++) {
        float xv = xb[(size_t)c * LL];
#pragma unroll
        for (int g = 0; g < 4; g++)
            acc[g] = fmaf(xv, w[(size_t)(og * 4 + g) * DM + c], acc[g]);
    }
#pragma unroll
    for (int g = 0; g < 4; g++) {
        int o = og * 4 + g;
        if (o < DI) xx[((size_t)b * DI + o) * LL + l] = acc[g];
        else        zs[((size_t)b * DI + (o - DI)) * LL + l] = silu_f(acc[g]);
    }
}

// ---- depthwise conv3x3+silu -> xxT[b][hw][d]; 32-wide d tiles (768 blocks)
__global__ void convT_k(const float* __restrict__ xx, const float* __restrict__ cw,
                        const float* __restrict__ cb, float* __restrict__ xxT) {
    __shared__ float tile[32][33];
    int bi = blockIdx.x;                 // 32 rows * 6 dtiles * 4 b
    int h0 = bi % 32;
    int dt = (bi / 32) % 6;
    int b = bi / 192;
    int d0 = dt * 32;
    int t = threadIdx.x;
    int wi = t & 31, dg = t >> 5;

#pragma unroll
    for (int pass = 0; pass < 4; pass++) {
        int di = pass * 8 + dg;
        int d = d0 + di;
        const float* xp = xx + ((size_t)b * DI + d) * LL;
        const float* wp = cw + d * 9;
        float acc = cb[d];
#pragma unroll
        for (int kh = 0; kh < 3; kh++) {
            int hh = h0 + kh - 1;
            if (hh < 0 || hh >= HH) continue;
#pragma unroll
            for (int kw = 0; kw < 3; kw++) {
                int ww2 = wi + kw - 1;
                if (ww2 < 0 || ww2 >= WW) continue;
                acc = fmaf(xp[hh * WW + ww2], wp[kh * 3 + kw], acc);
            }
        }
        tile[wi][di] = silu_f(acc);
    }
    __syncthreads();

    int di = t & 31, w8 = t >> 5;
#pragma unroll
    for (int rep = 0; rep < 4; rep++) {
        int w2 = rep * 8 + w8;
        xxT[((size_t)b * LL + h0 * 32 + w2) * DI + d0 + di] = tile[w2][di];
    }
}

// ---- x_dbl: tiled GEMM; stage 64 gathered rows of xxT, output [bk][l][38] -
__global__ void __launch_bounds__(512)
xdbl_k(const float* __restrict__ xxT, const float* __restrict__ xpw,
       float* __restrict__ xdbl) {
    __shared__ float tile[64 * 193];
    int blk = blockIdx.x;            // bk*16 + lt
    int bk = blk >> 4, lt = blk & 15;
    int k = bk & 3, b = bk >> 2;
    int t = threadIdx.x;

    const float* xb = xxT + (size_t)b * LL * DI;
#pragma unroll
    for (int i = 0; i < 6; i++) {
        int j4 = t + i * 512;
        int lr = j4 / 48;            // 48 float4 per row
        int d4 = j4 % 48;
        int hw = hw_of_l(k, lt * 64 + lr);
        float4 v = ((const float4*)(xb + (size_t)hw * DI))[d4];
        float* dst = &tile[lr * 193 + d4 * 4];
        dst[0] = v.x; dst[1] = v.y; dst[2] = v.z; dst[3] = v.w;
    }
    __syncthreads();

    int ll = t & 63;                 // lane -> l (2-way bank = free)
    int cg = t >> 6;                 // wave-uniform c-group 0..7
    int c0 = cg * 5;
    int wlim = (c0 + 5 <= 38) ? 5 : (38 - c0);   // 5,...,5,3
    const float* wk = xpw + (size_t)k * 38 * DI;

    float acc[5];
#pragma unroll
    for (int j = 0; j < 5; j++) acc[j] = 0.f;
    const float* xrow = &tile[ll * 193];
#pragma unroll 4
    for (int d = 0; d < DI; d++) {
        float xv = xrow[d];
#pragma unroll
        for (int j = 0; j < 5; j++) {
            int cc = c0 + j; cc = (cc > 37) ? 37 : cc;
            acc[j] = fmaf(xv, wk[(size_t)cc * DI + d], acc[j]);
        }
    }
    float* orow = xdbl + ((size_t)bk * LL + lt * 64 + ll) * 38;
#pragma unroll
    for (int j = 0; j < 5; j++)
        if (j < wlim) orow[c0 + j] = acc[j];
}

// ---- scan phase 1: LDS-staged u + xd, per-chunk local scan ----------------
__global__ void scan_p1(const float* __restrict__ xxT, const float* __restrict__ xdbl,
                        const float* __restrict__ dtw_g, const float* __restrict__ dtb_g,
                        const float* __restrict__ Alog,
                        float* __restrict__ Pst, float* __restrict__ Hloc) {
    __shared__ float u_tile[CS * 193];
    __shared__ float xd_tile[CS * 38];
    int blk = blockIdx.x;           // bk*NC + c
    int bk = blk / NC, c = blk % NC;
    int k = bk & 3, b = bk >> 2;
    int t = threadIdx.x;

    // stage u rows (snake-gathered, float4) and xd rows (contiguous)
    const float* xb = xxT + (size_t)b * LL * DI;
#pragma unroll
    for (int i = 0; i < 8; i++) {
        int j4 = t + i * 192;            // 1536 float4 = 32 rows * 48
        int s = j4 / 48, d4 = j4 % 48;
        int hw = hw_of_l(k, c * CS + s);
        float4 v = ((const float4*)(xb + (size_t)hw * DI))[d4];
        float* dst = &u_tile[s * 193 + d4 * 4];
        dst[0] = v.x; dst[1] = v.y; dst[2] = v.z; dst[3] = v.w;
    }
    const float* xdsrc = xdbl + ((size_t)bk * LL + c * CS) * 38;
    for (int i = t; i < CS * 38; i += 192) xd_tile[i] = xdsrc[i];
    __syncthreads();

    int d = t;
    int kd = k * DI + d;

    float A[NS];
#pragma unroll
    for (int n = 0; n < NS; n++) A[n] = -__expf(Alog[(size_t)kd * NS + n]);
    float dtw[RK];
#pragma unroll
    for (int r = 0; r < RK; r++) dtw[r] = dtw_g[(size_t)kd * RK + r];
    float dtb = dtb_g[kd];

    float h[NS], P[NS];
#pragma unroll
    for (int n = 0; n < NS; n++) { h[n] = 0.f; P[n] = 1.f; }

    for (int s = 0; s < CS; s++) {
        const float* xd = &xd_tile[s * 38];
        float dt = dtb;
#pragma unroll
        for (int r = 0; r < RK; r++) dt = fmaf(xd[r], dtw[r], dt);
        dt = (dt > 20.f) ? dt : __logf(1.f + __expf(dt));
        float du = dt * u_tile[s * 193 + d];
#pragma unroll
        for (int n = 0; n < NS; n++) {
            float a = __expf(dt * A[n]);
            h[n] = fmaf(a, h[n], du * xd[6 + n]);
            P[n] *= a;
        }
    }
    if (c < NC - 1) {   // last chunk's summary never consumed
        size_t base = ((size_t)blk * DI + d) * NS;
#pragma unroll
        for (int n = 0; n < NS; n++) { Pst[base + n] = P[n]; Hloc[base + n] = h[n]; }
    }
}

// ---- middle compose: 2 chains/thread (float2), depth-4 prefetch -----------
__global__ void scan_mid(const float* __restrict__ Pst, float* __restrict__ Hloc) {
    int gid = blockIdx.x * 256 + threadIdx.x;     // bk*1536 + j  (j = float2 idx)
    int bk = gid / 1536;
    int j = gid % 1536;
    const float2* Pp = (const float2*)(Pst + (size_t)bk * NC * (DI * NS)) + j;
    float2* Hp = (float2*)(Hloc + (size_t)bk * NC * (DI * NS)) + j;
    const int S = (DI * NS) / 2;     // stride between chunks in float2

    float2 h = make_float2(0.f, 0.f);
    float2 P[4], L[4];
#pragma unroll
    for (int q = 0; q < 4; q++) { P[q] = Pp[(size_t)q * S]; L[q] = Hp[(size_t)q * S]; }
    for (int c = 0; c < NC; c += 4) {
        float2 Pn[4], Ln[4];
        if (c + 4 < NC) {
#pragma unroll
            for (int q = 0; q < 4; q++) {
                Pn[q] = Pp[(size_t)(c + 4 + q) * S];
                Ln[q] = Hp[(size_t)(c + 4 + q) * S];
            }
        }
#pragma unroll
        for (int q = 0; q < 4; q++) {
            Hp[(size_t)(c + q) * S] = h;
            h.x = fmaf(P[q].x, h.x, L[q].x);
            h.y = fmaf(P[q].y, h.y, L[q].y);
        }
#pragma unroll
        for (int q = 0; q < 4; q++) { P[q] = Pn[q]; L[q] = Ln[q]; }
    }
}

// ---- scan phase 3: LDS-staged u + xd, final scan, y at spatial positions --
__global__ void scan_p3(const float* __restrict__ xxT, const float* __restrict__ xdbl,
                        const float* __restrict__ dtw_g, const float* __restrict__ dtb_g,
                        const float* __restrict__ Alog, const float* __restrict__ Ds,
                        const float* __restrict__ Hin, float* __restrict__ ysm) {
    __shared__ float u_tile[CS * 193];
    __shared__ float xd_tile[CS * 38];
    int blk = blockIdx.x;
    int bk = blk / NC, c = blk % NC;
    int k = bk & 3, b = bk >> 2;
    int t = threadIdx.x;

    const float* xb = xxT + (size_t)b * LL * DI;
#pragma unroll
    for (int i = 0; i < 8; i++) {
        int j4 = t + i * 192;
        int s = j4 / 48, d4 = j4 % 48;
        int hw = hw_of_l(k, c * CS + s);
        float4 v = ((const float4*)(xb + (size_t)hw * DI))[d4];
        float* dst = &u_tile[s * 193 + d4 * 4];
        dst[0] = v.x; dst[1] = v.y; dst[2] = v.z; dst[3] = v.w;
    }
    const float* xdsrc = xdbl + ((size_t)bk * LL + c * CS) * 38;
    for (int i = t; i < CS * 38; i += 192) xd_tile[i] = xdsrc[i];
    __syncthreads();

    int d = t;
    int kd = k * DI + d;

    float A[NS];
#pragma unroll
    for (int n = 0; n < NS; n++) A[n] = -__expf(Alog[(size_t)kd * NS + n]);
    float dtw[RK];
#pragma unroll
    for (int r = 0; r < RK; r++) dtw[r] = dtw_g[(size_t)kd * RK + r];
    float dtb = dtb_g[kd];
    float Dp = Ds[kd];

    float h[NS];
    size_t hbase = ((size_t)blk * DI + d) * NS;
#pragma unroll
    for (int n = 0; n < NS; n++) h[n] = Hin[hbase + n];

    float* yk = ysm + (size_t)bk * LL * DI;

    for (int s = 0; s < CS; s++) {
        const float* xd = &xd_tile[s * 38];
        float u = u_tile[s * 193 + d];
        float dt = dtb;
#pragma unroll
        for (int r = 0; r < RK; r++) dt = fmaf(xd[r], dtw[r], dt);
        dt = (dt > 20.f) ? dt : __logf(1.f + __expf(dt));
        float du = dt * u;
        float y = 0.f;
#pragma unroll
        for (int n = 0; n < NS; n++) {
            float a = __expf(dt * A[n]);
            h[n] = fmaf(a, h[n], du * xd[6 + n]);
            y = fmaf(h[n], xd[22 + n], y);
        }
        int hw = hw_of_l(k, c * CS + s);
        yk[(size_t)hw * DI + d] = fmaf(Dp, u, y);   // write at spatial position
    }
}

// ---- cross-merge: MT=8 -> 512 blocks, sequential reads, stats -------------
#define MT 8
__global__ void merge_k(const float* __restrict__ ysm, float* __restrict__ ym,
                        float* __restrict__ stats) {
    __shared__ float tile[MT][DI + 1];
    __shared__ float sh1[3], sh2[3];
    int b = blockIdx.y;
    int hw0 = blockIdx.x * MT;
    int d = threadIdx.x;
    const float* yb = ysm + (size_t)b * KK * LL * DI;

    float s1 = 0.f, s2 = 0.f;
#pragma unroll
    for (int hwi = 0; hwi < MT; hwi++) {
        int hw = hw0 + hwi;
        float v = yb[((size_t)0 * LL + hw) * DI + d]
                + yb[((size_t)1 * LL + hw) * DI + d]
                + yb[((size_t)2 * LL + hw) * DI + d]
                + yb[((size_t)3 * LL + hw) * DI + d];
        tile[hwi][d] = v;
        s1 += v; s2 = fmaf(v, v, s2);
    }
#pragma unroll
    for (int off = 32; off > 0; off >>= 1) {
        s1 += __shfl_down(s1, off);
        s2 += __shfl_down(s2, off);
    }
    int lane = threadIdx.x & 63, wid = threadIdx.x >> 6;
    if (lane == 0) { sh1[wid] = s1; sh2[wid] = s2; }
    __syncthreads();
    if (threadIdx.x == 0) {
        atomicAdd(&stats[b * 2],     sh1[0] + sh1[1] + sh1[2]);
        atomicAdd(&stats[b * 2 + 1], sh2[0] + sh2[1] + sh2[2]);
    }
#pragma unroll
    for (int rep = 0; rep < MT; rep++) {
        int j = rep * DI + threadIdx.x;
        int d2 = j >> 3;            // j / MT
        int hwi = j & (MT - 1);
        ym[((size_t)b * DI + d2) * LL + hw0 + hwi] = tile[hwi][d2];
    }
}

// ---- fused norm + gate + out projection: 3 outputs/thread (512 blocks) ----
__global__ void outz_k(const float* __restrict__ ym, const float* __restrict__ zs,
                       const float* __restrict__ g, const float* __restrict__ be,
                       const float* __restrict__ stats, const float* __restrict__ wo,
                       float* __restrict__ out) {
    int bi = blockIdx.x;                 // 4 lblk * 32 og * 4 b
    int t = threadIdx.x;
    int lb = bi & 3;
    int og = (bi >> 2) % 32;
    int b = bi / 128;
    int l = lb * 256 + t;

    const float Ninv = 1.f / (float)(DI * LL);
    float mu = stats[b * 2] * Ninv;
    float var = stats[b * 2 + 1] * Ninv - mu * mu;
    float rstd = rsqrtf(var + 1e-6f);

    const float* yb = ym + (size_t)b * DI * LL + l;
    const float* zb = zs + (size_t)b * DI * LL + l;
    float acc[3];
#pragma unroll
    for (int gg = 0; gg < 3; gg++) acc[gg] = 0.f;
    for (int c = 0; c < DI; c++) {
        float v = (yb[(size_t)c * LL] - mu) * rstd * g[c] + be[c];
        float yv = v * zb[(size_t)c * LL];
#pragma unroll
        for (int gg = 0; gg < 3; gg++)
            acc[gg] = fmaf(yv, wo[(size_t)(og * 3 + gg) * DI + c], acc[gg]);
    }
#pragma unroll
    for (int gg = 0; gg < 3; gg++)
        out[((size_t)b * DM + og * 3 + gg) * LL + l] = acc[gg];
}

extern "C" void kernel_launch(void* const* d_in, const int* in_sizes, int n_in,
                              void* d_out, int out_size, void* d_ws, size_t ws_size,
                              hipStream_t stream) {
    const float* x    = (const float*)d_in[0];
    const float* ipw  = (const float*)d_in[1];
    const float* cw   = (const float*)d_in[2];
    const float* cb   = (const float*)d_in[3];
    const float* xpw  = (const float*)d_in[4];
    const float* dtw  = (const float*)d_in[5];
    const float* dtb  = (const float*)d_in[6];
    const float* Alog = (const float*)d_in[7];
    const float* Ds   = (const float*)d_in[8];
    const float* gng  = (const float*)d_in[9];
    const float* gnb  = (const float*)d_in[10];
    const float* opw  = (const float*)d_in[11];
    float* out = (float*)d_out;

    float* ws = (float*)d_ws;
    const size_t o_xx   = 0;                                       // (→ ym)
    const size_t o_zs   = o_xx   + (size_t)Bsz * DI * LL;
    const size_t o_xxT  = o_zs   + (size_t)Bsz * DI * LL;
    const size_t o_xdbl = o_xxT  + (size_t)Bsz * LL * DI;
    const size_t o_P    = o_xdbl + (size_t)Bsz * KK * LL * 38;
    const size_t o_H    = o_P    + (size_t)Bsz * KK * NC * DI * NS;
    const size_t o_ysm  = o_H    + (size_t)Bsz * KK * NC * DI * NS;
    const size_t o_st   = o_ysm  + (size_t)Bsz * KK * LL * DI;

    float* xx    = ws + o_xx;
    float* zs    = ws + o_zs;
    float* xxT   = ws + o_xxT;
    float* xdbl  = ws + o_xdbl;
    float* Pst   = ws + o_P;
    float* Hst   = ws + o_H;
    float* ysm   = ws + o_ysm;
    float* stats = ws + o_st;
    float* ym = xx;    // xx dead after convT

    hipLaunchKernelGGL(in_proj_k, dim3(1536), dim3(256), 0, stream, x, ipw, xx, zs, stats);
    hipLaunchKernelGGL(convT_k, dim3(768), dim3(256), 0, stream, xx, cw, cb, xxT);
    hipLaunchKernelGGL(xdbl_k, dim3(256), dim3(512), 0, stream, xxT, xpw, xdbl);
    hipLaunchKernelGGL(scan_p1, dim3(Bsz * KK * NC), dim3(192), 0, stream,
                       xxT, xdbl, dtw, dtb, Alog, Pst, Hst);
    hipLaunchKernelGGL(scan_mid, dim3(96), dim3(256), 0, stream, Pst, Hst);
    hipLaunchKernelGGL(scan_p3, dim3(Bsz * KK * NC), dim3(192), 0, stream,
                       xxT, xdbl, dtw, dtb, Alog, Ds, Hst, ysm);
    hipLaunchKernelGGL(merge_k, dim3(LL / MT, Bsz), dim3(192), 0, stream, ysm, ym, stats);
    hipLaunchKernelGGL(outz_k, dim3(512), dim3(256), 0, stream, ym, zs, gng, gnb, stats, opw, out);
}

// Round 6
// 190.069 us; speedup vs baseline: 2.3651x; 1.0890x over previous
//
#include <hip/hip_runtime.h>
#include <math.h>

#define Bsz 4
#define DM 96
#define DI 192
#define NS 16
#define RK 6
#define KK 4
#define HH 32
#define WW 32
#define LL 1024
#define NC 32          // chunks along L
#define CS 32          // chunk size (NC*CS == LL)

__device__ __forceinline__ float silu_f(float x) { return x / (1.f + __expf(-x)); }

// forward snake map: scan position l -> flat spatial index hw for direction k
__device__ __forceinline__ int hw_of_l(int k, int l) {
    int a = l >> 5, r = l & 31;
    int m = (a & 1) ? 31 - r : r;
    int h, w;
    if (k < 2) { w = a; h = m; }      // vertical snake
    else       { h = a; w = m; }      // horizontal snake
    if (k & 1) { h = 31 - h; w = 31 - w; }
    return h * 32 + w;
}

// ---- in_proj: 4 outputs per thread (1536 blocks); zeroes stats ------------
__global__ void in_proj_k(const float* __restrict__ x, const float* __restrict__ w,
                          float* __restrict__ xx, float* __restrict__ zs,
                          float* __restrict__ stats) {
    int bi = blockIdx.x;                 // 4 lblk * 96 og * 4 b
    int t = threadIdx.x;
    if (bi == 0 && t < 2 * Bsz) stats[t] = 0.f;
    int lb = bi & 3;
    int og = (bi >> 2) % 96;
    int b = bi / 384;
    int l = lb * 256 + t;
    const float* xb = x + (size_t)b * DM * LL + l;
    float acc[4];
#pragma unroll
    for (int g = 0; g < 4; g++) acc[g] = 0.f;
    for (int c = 0; c < DM; c++) {
        float xv = xb[(size_t)c * LL];
#pragma unroll
        for (int g = 0; g < 4; g++)
            acc[g] = fmaf(xv, w[(size_t)(og * 4 + g) * DM + c], acc[g]);
    }
#pragma unroll
    for (int g = 0; g < 4; g++) {
        int o = og * 4 + g;
        if (o < DI) xx[((size_t)b * DI + o) * LL + l] = acc[g];
        else        zs[((size_t)b * DI + (o - DI)) * LL + l] = silu_f(acc[g]);
    }
}

// ---- depthwise conv3x3+silu -> xxT[b][hw][d]; 32-wide d tiles (768 blocks)
__global__ void convT_k(const float* __restrict__ xx, const float* __restrict__ cw,
                        const float* __restrict__ cb, float* __restrict__ xxT) {
    __shared__ float tile[32][33];
    int bi = blockIdx.x;                 // 32 rows * 6 dtiles * 4 b
    int h0 = bi % 32;
    int dt = (bi / 32) % 6;
    int b = bi / 192;
    int d0 = dt * 32;
    int t = threadIdx.x;
    int wi = t & 31, dg = t >> 5;

#pragma unroll
    for (int pass = 0; pass < 4; pass++) {
        int di = pass * 8 + dg;
        int d = d0 + di;
        const float* xp = xx + ((size_t)b * DI + d) * LL;
        const float* wp = cw + d * 9;
        float acc = cb[d];
#pragma unroll
        for (int kh = 0; kh < 3; kh++) {
            int hh = h0 + kh - 1;
            if (hh < 0 || hh >= HH) continue;
#pragma unroll
            for (int kw = 0; kw < 3; kw++) {
                int ww2 = wi + kw - 1;
                if (ww2 < 0 || ww2 >= WW) continue;
                acc = fmaf(xp[hh * WW + ww2], wp[kh * 3 + kw], acc);
            }
        }
        tile[wi][di] = silu_f(acc);
    }
    __syncthreads();

    int di = t & 31, w8 = t >> 5;
#pragma unroll
    for (int rep = 0; rep < 4; rep++) {
        int w2 = rep * 8 + w8;
        xxT[((size_t)b * LL + h0 * 32 + w2) * DI + d0 + di] = tile[w2][di];
    }
}

// ---- x_dbl: tiled GEMM; stage 64 gathered rows of xxT, output [bk][l][38] -
__global__ void __launch_bounds__(512)
xdbl_k(const float* __restrict__ xxT, const float* __restrict__ xpw,
       float* __restrict__ xdbl) {
    __shared__ float tile[64 * 193];
    int blk = blockIdx.x;            // bk*16 + lt
    int bk = blk >> 4, lt = blk & 15;
    int k = bk & 3, b = bk >> 2;
    int t = threadIdx.x;

    const float* xb = xxT + (size_t)b * LL * DI;
#pragma unroll
    for (int i = 0; i < 6; i++) {
        int j4 = t + i * 512;
        int lr = j4 / 48;            // 48 float4 per row
        int d4 = j4 % 48;
        int hw = hw_of_l(k, lt * 64 + lr);
        float4 v = ((const float4*)(xb + (size_t)hw * DI))[d4];
        float* dst = &tile[lr * 193 + d4 * 4];
        dst[0] = v.x; dst[1] = v.y; dst[2] = v.z; dst[3] = v.w;
    }
    __syncthreads();

    int ll = t & 63;                 // lane -> l (2-way bank = free)
    int cg = t >> 6;                 // wave-uniform c-group 0..7
    int c0 = cg * 5;
    int wlim = (c0 + 5 <= 38) ? 5 : (38 - c0);   // 5,...,5,3
    const float* wk = xpw + (size_t)k * 38 * DI;

    float acc[5];
#pragma unroll
    for (int j = 0; j < 5; j++) acc[j] = 0.f;
    const float* xrow = &tile[ll * 193];
#pragma unroll 4
    for (int d = 0; d < DI; d++) {
        float xv = xrow[d];
#pragma unroll
        for (int j = 0; j < 5; j++) {
            int cc = c0 + j; cc = (cc > 37) ? 37 : cc;
            acc[j] = fmaf(xv, wk[(size_t)cc * DI + d], acc[j]);
        }
    }
    float* orow = xdbl + ((size_t)bk * LL + lt * 64 + ll) * 38;
#pragma unroll
    for (int j = 0; j < 5; j++)
        if (j < wlim) orow[c0 + j] = acc[j];
}

// xd_tile row layout (40 floats, 16B aligned): [B(16) | C(16) | dt(6) | pad(2)]
// src xdbl row: [dt(0..5) | B(6..21) | C(22..37)] -> pj = (j<6) ? 32+j : j-6
#define XDP 40

// ---- scan phase 1: LDS-staged u + xd (vectorized), power-chain exp --------
__global__ void scan_p1(const float* __restrict__ xxT, const float* __restrict__ xdbl,
                        const float* __restrict__ dtw_g, const float* __restrict__ dtb_g,
                        const float* __restrict__ Alog,
                        float* __restrict__ Pst, float* __restrict__ Hloc) {
    __shared__ float u_tile[CS * 192];
    __shared__ float xd_tile[CS * XDP];
    int blk = blockIdx.x;           // bk*NC + c
    int bk = blk / NC, c = blk % NC;
    int k = bk & 3, b = bk >> 2;
    int t = threadIdx.x;

    const float* xb = xxT + (size_t)b * LL * DI;
#pragma unroll
    for (int i = 0; i < 8; i++) {
        int j4 = t + i * 192;            // 1536 float4 = 32 rows * 48
        int s = j4 / 48, d4 = j4 % 48;
        int hw = hw_of_l(k, c * CS + s);
        float4 v = ((const float4*)(xb + (size_t)hw * DI))[d4];
        ((float4*)(&u_tile[s * 192]))[d4] = v;   // aligned b128 store
    }
    const float* xdsrc = xdbl + ((size_t)bk * LL + c * CS) * 38;
    for (int i = t; i < CS * 38; i += 192) {
        int s = i / 38, j = i - s * 38;
        int pj = (j < 6) ? 32 + j : j - 6;
        xd_tile[s * XDP + pj] = xdsrc[i];
    }
    __syncthreads();

    int d = t;
    int kd = k * DI + d;
    float A0 = -__expf(Alog[(size_t)kd * NS]);
    bool pw = true;
#pragma unroll
    for (int n = 1; n < NS; n++) {
        float An = -__expf(Alog[(size_t)kd * NS + n]);
        pw = pw && (fabsf(An - (float)(n + 1) * A0) <= 1e-4f * (float)(n + 1));
    }
    float dtw[RK];
#pragma unroll
    for (int r = 0; r < RK; r++) dtw[r] = dtw_g[(size_t)kd * RK + r];
    float dtb = dtb_g[kd];

    float h[NS], P[NS];
#pragma unroll
    for (int n = 0; n < NS; n++) h[n] = 0.f;

    if (pw) {
        // A[n] = (n+1)*A0: a[n] = r^(n+1), per-chunk P[n] = R^(n+1)
        float R = 1.f;
        for (int s = 0; s < CS; s++) {
            const float4* xr = (const float4*)(&xd_tile[s * XDP]);
            float4 b0 = xr[0], b1 = xr[1], b2 = xr[2], b3 = xr[3];
            float4 q0 = xr[8], q1 = xr[9];
            float bb[16];
            bb[0]=b0.x; bb[1]=b0.y; bb[2]=b0.z; bb[3]=b0.w;
            bb[4]=b1.x; bb[5]=b1.y; bb[6]=b1.z; bb[7]=b1.w;
            bb[8]=b2.x; bb[9]=b2.y; bb[10]=b2.z; bb[11]=b2.w;
            bb[12]=b3.x; bb[13]=b3.y; bb[14]=b3.z; bb[15]=b3.w;
            float dt = dtb;
            dt = fmaf(q0.x, dtw[0], dt); dt = fmaf(q0.y, dtw[1], dt);
            dt = fmaf(q0.z, dtw[2], dt); dt = fmaf(q0.w, dtw[3], dt);
            dt = fmaf(q1.x, dtw[4], dt); dt = fmaf(q1.y, dtw[5], dt);
            dt = (dt > 20.f) ? dt : __logf(1.f + __expf(dt));
            float du = dt * u_tile[s * 192 + d];
            float r1 = __expf(dt * A0);
            float r2 = r1 * r1, r4 = r2 * r2, r8 = r4 * r4;
            float aa[16];
            aa[0] = r1; aa[1] = r2; aa[2] = r1 * r2; aa[3] = r4;
#pragma unroll
            for (int n = 0; n < 4; n++) aa[n + 4] = aa[n] * r4;
#pragma unroll
            for (int n = 0; n < 8; n++) aa[n + 8] = aa[n] * r8;
#pragma unroll
            for (int n = 0; n < NS; n++) h[n] = fmaf(aa[n], h[n], du * bb[n]);
            R *= r1;
        }
        float R2 = R * R, R4 = R2 * R2, R8 = R4 * R4;
        P[0] = R; P[1] = R2; P[2] = R * R2; P[3] = R4;
#pragma unroll
        for (int n = 0; n < 4; n++) P[n + 4] = P[n] * R4;
        P[7] = R8;
#pragma unroll
        for (int n = 0; n < 8; n++) P[n + 8] = P[n] * R8;
    } else {
        float A[NS];
#pragma unroll
        for (int n = 0; n < NS; n++) A[n] = -__expf(Alog[(size_t)kd * NS + n]);
#pragma unroll
        for (int n = 0; n < NS; n++) P[n] = 1.f;
        for (int s = 0; s < CS; s++) {
            const float4* xr = (const float4*)(&xd_tile[s * XDP]);
            float4 b0 = xr[0], b1 = xr[1], b2 = xr[2], b3 = xr[3];
            float4 q0 = xr[8], q1 = xr[9];
            float bb[16];
            bb[0]=b0.x; bb[1]=b0.y; bb[2]=b0.z; bb[3]=b0.w;
            bb[4]=b1.x; bb[5]=b1.y; bb[6]=b1.z; bb[7]=b1.w;
            bb[8]=b2.x; bb[9]=b2.y; bb[10]=b2.z; bb[11]=b2.w;
            bb[12]=b3.x; bb[13]=b3.y; bb[14]=b3.z; bb[15]=b3.w;
            float dt = dtb;
            dt = fmaf(q0.x, dtw[0], dt); dt = fmaf(q0.y, dtw[1], dt);
            dt = fmaf(q0.z, dtw[2], dt); dt = fmaf(q0.w, dtw[3], dt);
            dt = fmaf(q1.x, dtw[4], dt); dt = fmaf(q1.y, dtw[5], dt);
            dt = (dt > 20.f) ? dt : __logf(1.f + __expf(dt));
            float du = dt * u_tile[s * 192 + d];
#pragma unroll
            for (int n = 0; n < NS; n++) {
                float a = __expf(dt * A[n]);
                h[n] = fmaf(a, h[n], du * bb[n]);
                P[n] *= a;
            }
        }
    }
    if (c < NC - 1) {   // last chunk's summary never consumed
        size_t base = ((size_t)blk * DI + d) * NS;
#pragma unroll
        for (int n = 0; n < NS; n++) { Pst[base + n] = P[n]; Hloc[base + n] = h[n]; }
    }
}

// ---- middle compose: 2 chains/thread (float2), depth-4 prefetch -----------
__global__ void scan_mid(const float* __restrict__ Pst, float* __restrict__ Hloc) {
    int gid = blockIdx.x * 256 + threadIdx.x;     // bk*1536 + j  (j = float2 idx)
    int bk = gid / 1536;
    int j = gid % 1536;
    const float2* Pp = (const float2*)(Pst + (size_t)bk * NC * (DI * NS)) + j;
    float2* Hp = (float2*)(Hloc + (size_t)bk * NC * (DI * NS)) + j;
    const int S = (DI * NS) / 2;     // stride between chunks in float2

    float2 h = make_float2(0.f, 0.f);
    float2 P[4], L[4];
#pragma unroll
    for (int q = 0; q < 4; q++) { P[q] = Pp[(size_t)q * S]; L[q] = Hp[(size_t)q * S]; }
    for (int c = 0; c < NC; c += 4) {
        float2 Pn[4], Ln[4];
        if (c + 4 < NC) {
#pragma unroll
            for (int q = 0; q < 4; q++) {
                Pn[q] = Pp[(size_t)(c + 4 + q) * S];
                Ln[q] = Hp[(size_t)(c + 4 + q) * S];
            }
        }
#pragma unroll
        for (int q = 0; q < 4; q++) {
            Hp[(size_t)(c + q) * S] = h;
            h.x = fmaf(P[q].x, h.x, L[q].x);
            h.y = fmaf(P[q].y, h.y, L[q].y);
        }
#pragma unroll
        for (int q = 0; q < 4; q++) { P[q] = Pn[q]; L[q] = Ln[q]; }
    }
}

// ---- scan phase 3: LDS-staged, power-chain exp, y at spatial positions ----
__global__ void scan_p3(const float* __restrict__ xxT, const float* __restrict__ xdbl,
                        const float* __restrict__ dtw_g, const float* __restrict__ dtb_g,
                        const float* __restrict__ Alog, const float* __restrict__ Ds,
                        const float* __restrict__ Hin, float* __restrict__ ysm) {
    __shared__ float u_tile[CS * 192];
    __shared__ float xd_tile[CS * XDP];
    int blk = blockIdx.x;
    int bk = blk / NC, c = blk % NC;
    int k = bk & 3, b = bk >> 2;
    int t = threadIdx.x;

    const float* xb = xxT + (size_t)b * LL * DI;
#pragma unroll
    for (int i = 0; i < 8; i++) {
        int j4 = t + i * 192;
        int s = j4 / 48, d4 = j4 % 48;
        int hw = hw_of_l(k, c * CS + s);
        float4 v = ((const float4*)(xb + (size_t)hw * DI))[d4];
        ((float4*)(&u_tile[s * 192]))[d4] = v;
    }
    const float* xdsrc = xdbl + ((size_t)bk * LL + c * CS) * 38;
    for (int i = t; i < CS * 38; i += 192) {
        int s = i / 38, j = i - s * 38;
        int pj = (j < 6) ? 32 + j : j - 6;
        xd_tile[s * XDP + pj] = xdsrc[i];
    }
    __syncthreads();

    int d = t;
    int kd = k * DI + d;
    float A0 = -__expf(Alog[(size_t)kd * NS]);
    bool pw = true;
#pragma unroll
    for (int n = 1; n < NS; n++) {
        float An = -__expf(Alog[(size_t)kd * NS + n]);
        pw = pw && (fabsf(An - (float)(n + 1) * A0) <= 1e-4f * (float)(n + 1));
    }
    float dtw[RK];
#pragma unroll
    for (int r = 0; r < RK; r++) dtw[r] = dtw_g[(size_t)kd * RK + r];
    float dtb = dtb_g[kd];
    float Dp = Ds[kd];

    float h[NS];
    size_t hbase = ((size_t)blk * DI + d) * NS;
#pragma unroll
    for (int n = 0; n < NS; n++) h[n] = Hin[hbase + n];

    float* yk = ysm + (size_t)bk * LL * DI;

    if (pw) {
        for (int s = 0; s < CS; s++) {
            const float4* xr = (const float4*)(&xd_tile[s * XDP]);
            float4 b0 = xr[0], b1 = xr[1], b2 = xr[2], b3 = xr[3];
            float4 c0 = xr[4], c1 = xr[5], c2 = xr[6], c3 = xr[7];
            float4 q0 = xr[8], q1 = xr[9];
            float bb[16], cc[16];
            bb[0]=b0.x; bb[1]=b0.y; bb[2]=b0.z; bb[3]=b0.w;
            bb[4]=b1.x; bb[5]=b1.y; bb[6]=b1.z; bb[7]=b1.w;
            bb[8]=b2.x; bb[9]=b2.y; bb[10]=b2.z; bb[11]=b2.w;
            bb[12]=b3.x; bb[13]=b3.y; bb[14]=b3.z; bb[15]=b3.w;
            cc[0]=c0.x; cc[1]=c0.y; cc[2]=c0.z; cc[3]=c0.w;
            cc[4]=c1.x; cc[5]=c1.y; cc[6]=c1.z; cc[7]=c1.w;
            cc[8]=c2.x; cc[9]=c2.y; cc[10]=c2.z; cc[11]=c2.w;
            cc[12]=c3.x; cc[13]=c3.y; cc[14]=c3.z; cc[15]=c3.w;
            float dt = dtb;
            dt = fmaf(q0.x, dtw[0], dt); dt = fmaf(q0.y, dtw[1], dt);
            dt = fmaf(q0.z, dtw[2], dt); dt = fmaf(q0.w, dtw[3], dt);
            dt = fmaf(q1.x, dtw[4], dt); dt = fmaf(q1.y, dtw[5], dt);
            dt = (dt > 20.f) ? dt : __logf(1.f + __expf(dt));
            float u = u_tile[s * 192 + d];
            float du = dt * u;
            float r1 = __expf(dt * A0);
            float r2 = r1 * r1, r4 = r2 * r2, r8 = r4 * r4;
            float aa[16];
            aa[0] = r1; aa[1] = r2; aa[2] = r1 * r2; aa[3] = r4;
#pragma unroll
            for (int n = 0; n < 4; n++) aa[n + 4] = aa[n] * r4;
#pragma unroll
            for (int n = 0; n < 8; n++) aa[n + 8] = aa[n] * r8;
            float y = 0.f;
#pragma unroll
            for (int n = 0; n < NS; n++) {
                h[n] = fmaf(aa[n], h[n], du * bb[n]);
                y = fmaf(h[n], cc[n], y);
            }
            int hw = hw_of_l(k, c * CS + s);
            yk[(size_t)hw * DI + d] = fmaf(Dp, u, y);
        }
    } else {
        float A[NS];
#pragma unroll
        for (int n = 0; n < NS; n++) A[n] = -__expf(Alog[(size_t)kd * NS + n]);
        for (int s = 0; s < CS; s++) {
            const float4* xr = (const float4*)(&xd_tile[s * XDP]);
            float4 b0 = xr[0], b1 = xr[1], b2 = xr[2], b3 = xr[3];
            float4 c0 = xr[4], c1 = xr[5], c2 = xr[6], c3 = xr[7];
            float4 q0 = xr[8], q1 = xr[9];
            float bb[16], cc[16];
            bb[0]=b0.x; bb[1]=b0.y; bb[2]=b0.z; bb[3]=b0.w;
            bb[4]=b1.x; bb[5]=b1.y; bb[6]=b1.z; bb[7]=b1.w;
            bb[8]=b2.x; bb[9]=b2.y; bb[10]=b2.z; bb[11]=b2.w;
            bb[12]=b3.x; bb[13]=b3.y; bb[14]=b3.z; bb[15]=b3.w;
            cc[0]=c0.x; cc[1]=c0.y; cc[2]=c0.z; cc[3]=c0.w;
            cc[4]=c1.x; cc[5]=c1.y; cc[6]=c1.z; cc[7]=c1.w;
            cc[8]=c2.x; cc[9]=c2.y; cc[10]=c2.z; cc[11]=c2.w;
            cc[12]=c3.x; cc[13]=c3.y; cc[14]=c3.z; cc[15]=c3.w;
            float dt = dtb;
            dt = fmaf(q0.x, dtw[0], dt); dt = fmaf(q0.y, dtw[1], dt);
            dt = fmaf(q0.z, dtw[2], dt); dt = fmaf(q0.w, dtw[3], dt);
            dt = fmaf(q1.x, dtw[4], dt); dt = fmaf(q1.y, dtw[5], dt);
            dt = (dt > 20.f) ? dt : __logf(1.f + __expf(dt));
            float u = u_tile[s * 192 + d];
            float du = dt * u;
            float y = 0.f;
#pragma unroll
            for (int n = 0; n < NS; n++) {
                float a = __expf(dt * A[n]);
                h[n] = fmaf(a, h[n], du * bb[n]);
                y = fmaf(h[n], cc[n], y);
            }
            int hw = hw_of_l(k, c * CS + s);
            yk[(size_t)hw * DI + d] = fmaf(Dp, u, y);
        }
    }
}

// ---- cross-merge: MT=8 -> 512 blocks, sequential reads, stats -------------
#define MT 8
__global__ void merge_k(const float* __restrict__ ysm, float* __restrict__ ym,
                        float* __restrict__ stats) {
    __shared__ float tile[MT][DI + 1];
    __shared__ float sh1[3], sh2[3];
    int b = blockIdx.y;
    int hw0 = blockIdx.x * MT;
    int d = threadIdx.x;
    const float* yb = ysm + (size_t)b * KK * LL * DI;

    float s1 = 0.f, s2 = 0.f;
#pragma unroll
    for (int hwi = 0; hwi < MT; hwi++) {
        int hw = hw0 + hwi;
        float v = yb[((size_t)0 * LL + hw) * DI + d]
                + yb[((size_t)1 * LL + hw) * DI + d]
                + yb[((size_t)2 * LL + hw) * DI + d]
                + yb[((size_t)3 * LL + hw) * DI + d];
        tile[hwi][d] = v;
        s1 += v; s2 = fmaf(v, v, s2);
    }
#pragma unroll
    for (int off = 32; off > 0; off >>= 1) {
        s1 += __shfl_down(s1, off);
        s2 += __shfl_down(s2, off);
    }
    int lane = threadIdx.x & 63, wid = threadIdx.x >> 6;
    if (lane == 0) { sh1[wid] = s1; sh2[wid] = s2; }
    __syncthreads();
    if (threadIdx.x == 0) {
        atomicAdd(&stats[b * 2],     sh1[0] + sh1[1] + sh1[2]);
        atomicAdd(&stats[b * 2 + 1], sh2[0] + sh2[1] + sh2[2]);
    }
#pragma unroll
    for (int rep = 0; rep < MT; rep++) {
        int j = rep * DI + threadIdx.x;
        int d2 = j >> 3;            // j / MT
        int hwi = j & (MT - 1);
        ym[((size_t)b * DI + d2) * LL + hw0 + hwi] = tile[hwi][d2];
    }
}

// ---- fused norm + gate + out projection: 3 outputs/thread (512 blocks) ----
__global__ void outz_k(const float* __restrict__ ym, const float* __restrict__ zs,
                       const float* __restrict__ g, const float* __restrict__ be,
                       const float* __restrict__ stats, const float* __restrict__ wo,
                       float* __restrict__ out) {
    int bi = blockIdx.x;                 // 4 lblk * 32 og * 4 b
    int t = threadIdx.x;
    int lb = bi & 3;
    int og = (bi >> 2) % 32;
    int b = bi / 128;
    int l = lb * 256 + t;

    const float Ninv = 1.f / (float)(DI * LL);
    float mu = stats[b * 2] * Ninv;
    float var = stats[b * 2 + 1] * Ninv - mu * mu;
    float rstd = rsqrtf(var + 1e-6f);

    const float* yb = ym + (size_t)b * DI * LL + l;
    const float* zb = zs + (size_t)b * DI * LL + l;
    float acc[3];
#pragma unroll
    for (int gg = 0; gg < 3; gg++) acc[gg] = 0.f;
    for (int c = 0; c < DI; c++) {
        float v = (yb[(size_t)c * LL] - mu) * rstd * g[c] + be[c];
        float yv = v * zb[(size_t)c * LL];
#pragma unroll
        for (int gg = 0; gg < 3; gg++)
            acc[gg] = fmaf(yv, wo[(size_t)(og * 3 + gg) * DI + c], acc[gg]);
    }
#pragma unroll
    for (int gg = 0; gg < 3; gg++)
        out[((size_t)b * DM + og * 3 + gg) * LL + l] = acc[gg];
}

extern "C" void kernel_launch(void* const* d_in, const int* in_sizes, int n_in,
                              void* d_out, int out_size, void* d_ws, size_t ws_size,
                              hipStream_t stream) {
    const float* x    = (const float*)d_in[0];
    const float* ipw  = (const float*)d_in[1];
    const float* cw   = (const float*)d_in[2];
    const float* cb   = (const float*)d_in[3];
    const float* xpw  = (const float*)d_in[4];
    const float* dtw  = (const float*)d_in[5];
    const float* dtb  = (const float*)d_in[6];
    const float* Alog = (const float*)d_in[7];
    const float* Ds   = (const float*)d_in[8];
    const float* gng  = (const float*)d_in[9];
    const float* gnb  = (const float*)d_in[10];
    const float* opw  = (const float*)d_in[11];
    float* out = (float*)d_out;

    float* ws = (float*)d_ws;
    const size_t o_xx   = 0;                                       // (→ ym)
    const size_t o_zs   = o_xx   + (size_t)Bsz * DI * LL;
    const size_t o_xxT  = o_zs   + (size_t)Bsz * DI * LL;
    const size_t o_xdbl = o_xxT  + (size_t)Bsz * LL * DI;
    const size_t o_P    = o_xdbl + (size_t)Bsz * KK * LL * 38;
    const size_t o_H    = o_P    + (size_t)Bsz * KK * NC * DI * NS;
    const size_t o_ysm  = o_H    + (size_t)Bsz * KK * NC * DI * NS;
    const size_t o_st   = o_ysm  + (size_t)Bsz * KK * LL * DI;

    float* xx    = ws + o_xx;
    float* zs    = ws + o_zs;
    float* xxT   = ws + o_xxT;
    float* xdbl  = ws + o_xdbl;
    float* Pst   = ws + o_P;
    float* Hst   = ws + o_H;
    float* ysm   = ws + o_ysm;
    float* stats = ws + o_st;
    float* ym = xx;    // xx dead after convT

    hipLaunchKernelGGL(in_proj_k, dim3(1536), dim3(256), 0, stream, x, ipw, xx, zs, stats);
    hipLaunchKernelGGL(convT_k, dim3(768), dim3(256), 0, stream, xx, cw, cb, xxT);
    hipLaunchKernelGGL(xdbl_k, dim3(256), dim3(512), 0, stream, xxT, xpw, xdbl);
    hipLaunchKernelGGL(scan_p1, dim3(Bsz * KK * NC), dim3(192), 0, stream,
                       xxT, xdbl, dtw, dtb, Alog, Pst, Hst);
    hipLaunchKernelGGL(scan_mid, dim3(96), dim3(256), 0, stream, Pst, Hst);
    hipLaunchKernelGGL(scan_p3, dim3(Bsz * KK * NC), dim3(192), 0, stream,
                       xxT, xdbl, dtw, dtb, Alog, Ds, Hst, ysm);
    hipLaunchKernelGGL(merge_k, dim3(LL / MT, Bsz), dim3(192), 0, stream, ysm, ym, stats);
    hipLaunchKernelGGL(outz_k, dim3(512), dim3(256), 0, stream, ym, zs, gng, gnb, stats, opw, out);
}